// Round 7
// baseline (298.746 us; speedup 1.0000x reference)
//
#include <hip/hip_runtime.h>

// Problem constants
#define NB 4
#define NA 3
#define NS 1024
#define NHID 768
#define NHEADS 12
#define HD 64

typedef __bf16 bf16_t;
typedef __bf16 bf16x8 __attribute__((ext_vector_type(8)));
typedef __bf16 bf16x4 __attribute__((ext_vector_type(4)));
typedef float f32x4 __attribute__((ext_vector_type(4)));

#define MFMA(a, b, c) __builtin_amdgcn_mfma_f32_16x16x32_bf16(a, b, c, 0, 0, 0)

static __device__ __forceinline__ bf16x8 load8(const bf16_t* p) {
    return *reinterpret_cast<const bf16x8*>(p);
}

// async global->LDS, 16B per lane. LDS dest = wave-uniform base + lane*16.
typedef __attribute__((address_space(3))) unsigned int u32_lds;
typedef __attribute__((address_space(1))) unsigned int u32_glb;
static __device__ __forceinline__ void gl_lds16(const void* g, void* lds_base_uniform) {
    __builtin_amdgcn_global_load_lds((const u32_glb*)g, (u32_lds*)lds_base_uniform, 16, 0, 0);
}

static __device__ __forceinline__ bf16x8 cvt8(f32x4 lo, f32x4 hi) {
    bf16x8 r;
    r[0] = (bf16_t)lo[0]; r[1] = (bf16_t)lo[1]; r[2] = (bf16_t)lo[2]; r[3] = (bf16_t)lo[3];
    r[4] = (bf16_t)hi[0]; r[5] = (bf16_t)hi[1]; r[6] = (bf16_t)hi[2]; r[7] = (bf16_t)hi[3];
    return r;
}

// ---------------------------------------------------------------------------
// Vp layout (validated R14/R15): per (bh,a): 32 sb-blocks of 4KB:
//   byte = (bh*NA+a)*131072 + sb*4096 + dt*1024 + (q*16 + l)*16 + e*2
// holding V[d = dt*16+l][s = sb*32 + s5] with s5 = (e>>2)*16 + q*4 + (e&3).
// ---------------------------------------------------------------------------

// ---------------------------------------------------------------------------
// fp32 -> bf16 bulk conversion, up to 6 segments.
// ---------------------------------------------------------------------------
__global__ __launch_bounds__(256) void cvt6(
    const float* __restrict__ s0, bf16_t* __restrict__ d0, int c0,
    const float* __restrict__ s1, bf16_t* __restrict__ d1, int c1,
    const float* __restrict__ s2, bf16_t* __restrict__ d2, int c2,
    const float* __restrict__ s3, bf16_t* __restrict__ d3, int c3,
    const float* __restrict__ s4, bf16_t* __restrict__ d4, int c4,
    const float* __restrict__ s5, bf16_t* __restrict__ d5, int c5)
{
    const int bid = blockIdx.x;
    const float* s; bf16_t* d; int rel;
    if      (bid < c0) { s = s0; d = d0; rel = bid; }
    else if (bid < c1) { s = s1; d = d1; rel = bid - c0; }
    else if (bid < c2) { s = s2; d = d2; rel = bid - c1; }
    else if (bid < c3) { s = s3; d = d3; rel = bid - c2; }
    else if (bid < c4) { s = s4; d = d4; rel = bid - c3; }
    else               { s = s5; d = d5; rel = bid - c4; }
    const int t = threadIdx.x;
#pragma unroll
    for (int k = 0; k < 4; k++) {
        size_t u = (size_t)rel * 1024 + k * 256 + t;   // f32x4 unit index
        f32x4 v = reinterpret_cast<const f32x4*>(s)[u];
        bf16x4 o;
        o[0] = (bf16_t)v[0]; o[1] = (bf16_t)v[1];
        o[2] = (bf16_t)v[2]; o[3] = (bf16_t)v[3];
        reinterpret_cast<bf16x4*>(d)[u] = o;
    }
}

// ---------------------------------------------------------------------------
// R16 gemm8 (unchanged): 256x128 tile, BK=64, 8 waves, 3-buf depth-2
// counted-vmcnt, 2 phases/iter with setprio around MFMA clusters.
// Blocks [0,576): KV. [576,672): Q via X2/W2/bias2.
// ---------------------------------------------------------------------------
__global__ __launch_bounds__(512) void gemm8(
    const bf16_t* __restrict__ X,
    const bf16_t* __restrict__ W0, const bf16_t* __restrict__ W1,
    const float* __restrict__ bias0, const float* __restrict__ bias1,
    bf16_t* __restrict__ outK, bf16_t* __restrict__ outV,
    const bf16_t* __restrict__ X2, const bf16_t* __restrict__ W2,
    const float* __restrict__ bias2, bf16_t* __restrict__ outQ)
{
    constexpr int BUFSZ = 49152;                  // A 32K + B 16K
    __shared__ __align__(16) char smem[3 * BUFSZ];

    const int t = threadIdx.x;
    const int lane = t & 63, w = t >> 6;          // w in [0,8)
    const int quad = lane >> 4, l15 = lane & 15;
    const int wm = w >> 1, wn = w & 1;            // 4M x 2N wave grid

    int emode = 1, nt = 12, bid = blockIdx.x;
    const bf16_t* Xp = X;
    const bf16_t* Wp = W0;
    const float*  b0 = bias0;
    if (bid >= 576) {                             // Q region
        emode = 0; nt = 6; bid -= 576;
        Xp = X2; Wp = W2; b0 = bias2;
    }

    // XCD-aware swizzle
    const int xcd = bid & 7, jj = bid >> 3;
    const int n_t = jj % nt, slab = jj / nt;
    const int m0 = (slab * 8 + xcd) * 256;
    const int n0 = n_t * 128;

    const bf16_t* Wsel = (emode == 1 && n0 >= 768) ? W1 : Wp;
    const int n0b = (emode == 1 && n0 >= 768) ? n0 - 768 : n0;

    const bf16_t* sp[6];
    int loff[6];
#pragma unroll
    for (int i = 0; i < 6; i++) {
        int g = w * 6 + i;
        loff[i] = g * 1024;
        if (g < 32) {
            int ks = g >> 4, mt = g & 15;
            sp[i] = Xp + (size_t)(m0 + mt * 16 + l15) * NHID + ks * 32 + quad * 8;
        } else {
            int gb = g - 32;
            int ks = gb >> 3, ntile = gb & 7;
            sp[i] = Wsel + (size_t)(n0b + ntile * 16 + l15) * NHID + ks * 32 + quad * 8;
        }
    }

    auto stage_half = [&](char* base, int h) {     // 3 instrs per half
#pragma unroll
        for (int i = 0; i < 3; i++) {
            int idx = h * 3 + i;
            gl_lds16(sp[idx], base + loff[idx]);
            sp[idx] += 64;                         // BK=64 elements
        }
    };

    f32x4 acc[4][4];
#pragma unroll
    for (int i = 0; i < 4; i++)
#pragma unroll
        for (int j = 0; j < 4; j++) acc[i][j] = 0.0f;

    constexpr int KITER = NHID / 64;               // 12
    stage_half(smem, 0);          stage_half(smem, 1);           // stage(0)
    stage_half(smem + BUFSZ, 0);  stage_half(smem + BUFSZ, 1);   // stage(1)

    for (int it = 0; it < KITER; ++it) {
        if (it == KITER - 1) asm volatile("s_waitcnt vmcnt(0)" ::: "memory");
        else                 asm volatile("s_waitcnt vmcnt(6)" ::: "memory");
        __builtin_amdgcn_s_barrier();              // all waves' stage(it) done

        const char* rb = smem + (it % 3) * BUFSZ;
        char* pb = smem + ((it + 2) % 3) * BUFSZ;
        const bool dostage = (it + 2 < KITER);

#pragma unroll
        for (int ks = 0; ks < 2; ++ks) {           // 2 phases per iteration
            bf16x8 af[4], bfr[4];
#pragma unroll
            for (int i = 0; i < 4; i++)
                af[i] = *(const bf16x8*)(rb + (ks * 16 + wm * 4 + i) * 1024 + lane * 16);
#pragma unroll
            for (int j = 0; j < 4; j++)
                bfr[j] = *(const bf16x8*)(rb + 32768 + (ks * 8 + wn * 4 + j) * 1024 + lane * 16);
            if (dostage) stage_half(pb, ks);
            __builtin_amdgcn_s_setprio(1);
#pragma unroll
            for (int i = 0; i < 4; i++)
#pragma unroll
                for (int j = 0; j < 4; j++)
                    acc[i][j] = MFMA(af[i], bfr[j], acc[i][j]);
            __builtin_amdgcn_s_setprio(0);
            if (ks == 0) __builtin_amdgcn_s_barrier();   // phase boundary
        }
    }

    // ---- epilogue: per-wave 64x64 at (m0 + wm*64, n0 + wn*64) ----
#pragma unroll
    for (int i = 0; i < 4; i++) {
#pragma unroll
        for (int j = 0; j < 4; j++) {
            const int n = n0 + wn * 64 + j * 16 + l15;
            float bn;
            if (emode == 1) bn = (n < 768) ? b0[n] : bias1[n - 768];
            else            bn = b0[n];
            if (emode == 1 && n >= 768) {
                // Vp layout, bf16x4-packed (rg -> consecutive e-slots)
                const int m = m0 + wm * 64 + i * 16 + quad * 4;
                int b = m / (NA * NS);
                int rem = m - b * (NA * NS);
                int a = rem >> 10, s = rem & 1023;
                int hh = (n - 768) >> 6;
                bf16x4 pk;
#pragma unroll
                for (int rg = 0; rg < 4; rg++) pk[rg] = (bf16_t)(acc[i][j][rg] + bn);
                char* dst = (char*)outV + (size_t)((b * NHEADS + hh) * NA + a) * 131072
                            + (size_t)(s >> 5) * 4096 + j * 1024
                            + (quad * 16 + l15) * 16 + (i & 1) * 8;
                *reinterpret_cast<bf16x4*>(dst) = pk;
            } else {
#pragma unroll
                for (int rg = 0; rg < 4; rg++) {
                    const int m = m0 + wm * 64 + i * 16 + quad * 4 + rg;
                    float v = acc[i][j][rg] + bn;
                    if (emode == 0) {
                        int b = m >> 10, s = m & 1023, hh = n >> 6, d = n & 63;
                        outQ[(((size_t)(b * NHEADS + hh) * NS) + s) * HD + d] = (bf16_t)v;
                    } else {
                        int b = m / (NA * NS);
                        int rem = m - b * (NA * NS);
                        int a = rem >> 10, s = rem & 1023;
                        int hh = n >> 6, d = n & 63;
                        outK[((((size_t)(b * NHEADS + hh) * NA + a) * NS) + s) * HD + d] = (bf16_t)v;
                    }
                }
            }
        }
    }
}

// ---------------------------------------------------------------------------
// Projection GEMM (R15 structure), used for O-proj and tiers 2/3.
// 128x128 tile, BK=32, 4 waves, 2 buffers + 2 raw barriers + counted vmcnt.
// ---------------------------------------------------------------------------
template <int MODE, int NT, bool ABF, bool BBF>
__global__ __launch_bounds__(256) void proj_gemm(
    const void* __restrict__ Xv,
    const void* __restrict__ W0v, const void* __restrict__ W1v,
    const float* __restrict__ bias0, const float* __restrict__ bias1,
    const float* __restrict__ resid,
    bf16_t* __restrict__ out0, bf16_t* __restrict__ out1,
    float* __restrict__ outf)
{
    constexpr int ASZ   = ABF ? 8192 : 16384;
    constexpr int BSZ   = BBF ? 8192 : 16384;
    constexpr int BUFSZ = ASZ + BSZ;
    constexpr int LPS   = (ABF ? 2 : 4) + (BBF ? 2 : 4);
    __shared__ __align__(16) char smem[2 * BUFSZ];

    const int t = threadIdx.x;
    const int lane = t & 63, w = t >> 6;
    const int quad = lane >> 4, l15 = lane & 15;
    const int wm = w >> 1, wn = w & 1;

    const int bid = blockIdx.x;
    const int xcd = bid & 7, jj = bid >> 3;
    const int n_t = jj % NT, slab = jj / NT;
    const int m0 = (slab * 8 + xcd) * 128;
    const int n0 = n_t * 128;

    const void* Wselv = (MODE == 1 && n0 >= 768) ? W1v : W0v;
    const int n0b = (MODE == 1 && n0 >= 768) ? n0 - 768 : n0;

    const int srow  = lane >> 3;
    const int schnk = (lane & 7) ^ srow;
    const float*  Apf[4];
    const bf16_t* Apb[2];
    const float*  Bpf[4];
    const bf16_t* Bpb[2];
    if constexpr (ABF) {
        const bf16_t* X = (const bf16_t*)Xv;
#pragma unroll
        for (int i = 0; i < 2; i++) {
            int g = w * 2 + i;
            Apb[i] = X + (size_t)(m0 + g * 16 + l15) * NHID + quad * 8;
        }
    } else {
        const float* X = (const float*)Xv;
#pragma unroll
        for (int i = 0; i < 4; i++) {
            int g = w * 4 + i;
            Apf[i] = X + (size_t)(m0 + g * 8 + srow) * NHID + schnk * 4;
        }
    }
    if constexpr (BBF) {
        const bf16_t* Wb = (const bf16_t*)Wselv;
#pragma unroll
        for (int i = 0; i < 2; i++) {
            int g = w * 2 + i;
            Bpb[i] = Wb + (size_t)(n0b + g * 16 + l15) * NHID + quad * 8;
        }
    } else {
        const float* Wf = (const float*)Wselv;
#pragma unroll
        for (int i = 0; i < 4; i++) {
            int g = w * 4 + i;
            Bpf[i] = Wf + (size_t)(n0b + g * 8 + srow) * NHID + schnk * 4;
        }
    }

    auto stage = [&](char* base) {
        char* Ab = base;
        char* Bb = base + ASZ;
        if constexpr (ABF) {
#pragma unroll
            for (int i = 0; i < 2; i++) { gl_lds16(Apb[i], Ab + (w * 2 + i) * 1024); Apb[i] += 32; }
        } else {
#pragma unroll
            for (int i = 0; i < 4; i++) { gl_lds16(Apf[i], Ab + (w * 4 + i) * 1024); Apf[i] += 32; }
        }
        if constexpr (BBF) {
#pragma unroll
            for (int i = 0; i < 2; i++) { gl_lds16(Bpb[i], Bb + (w * 2 + i) * 1024); Bpb[i] += 32; }
        } else {
#pragma unroll
            for (int i = 0; i < 4; i++) { gl_lds16(Bpf[i], Bb + (w * 4 + i) * 1024); Bpf[i] += 32; }
        }
    };

    auto wait_one = [&]() {
        if constexpr (LPS == 4)      asm volatile("s_waitcnt vmcnt(4)" ::: "memory");
        else if constexpr (LPS == 6) asm volatile("s_waitcnt vmcnt(6)" ::: "memory");
        else                         asm volatile("s_waitcnt vmcnt(8)" ::: "memory");
    };

    f32x4 acc[4][4];
#pragma unroll
    for (int i = 0; i < 4; i++)
#pragma unroll
        for (int j = 0; j < 4; j++) acc[i][j] = 0.0f;

    constexpr int KITER = NHID / 32;   // 24
    stage(smem);

    for (int it = 0; it < KITER; ++it) {
        if (it + 1 < KITER) {
            stage(smem + ((it + 1) & 1) * BUFSZ);
            wait_one();
        } else {
            asm volatile("s_waitcnt vmcnt(0)" ::: "memory");
        }
        __builtin_amdgcn_s_barrier();

        char* Ab = smem + (it & 1) * BUFSZ;
        char* Bb = Ab + ASZ;

        bf16x8 af[4], bfr[4];
        const int pl = (2 * quad) ^ (l15 & 7);
#pragma unroll
        for (int i = 0; i < 4; i++) {
            if constexpr (ABF) {
                int mt = wm * 4 + i;
                af[i] = *(const bf16x8*)(Ab + (mt * 64 + lane) * 16);
            } else {
                int R = (wm * 4 + i) * 16 + l15;
                f32x4 lo = *(const f32x4*)(Ab + R * 128 + pl * 16);
                f32x4 hi = *(const f32x4*)(Ab + R * 128 + (pl ^ 1) * 16);
                af[i] = cvt8(lo, hi);
            }
        }
#pragma unroll
        for (int j = 0; j < 4; j++) {
            if constexpr (BBF) {
                int ntj = wn * 4 + j;
                bfr[j] = *(const bf16x8*)(Bb + (ntj * 64 + lane) * 16);
            } else {
                int R = (wn * 4 + j) * 16 + l15;
                f32x4 lo = *(const f32x4*)(Bb + R * 128 + pl * 16);
                f32x4 hi = *(const f32x4*)(Bb + R * 128 + (pl ^ 1) * 16);
                bfr[j] = cvt8(lo, hi);
            }
        }
#pragma unroll
        for (int i = 0; i < 4; i++)
#pragma unroll
            for (int j = 0; j < 4; j++)
                acc[i][j] = MFMA(af[i], bfr[j], acc[i][j]);
        __builtin_amdgcn_s_barrier();
    }

#pragma unroll
    for (int i = 0; i < 4; i++) {
#pragma unroll
        for (int j = 0; j < 4; j++) {
            const int n = n0 + wn * 64 + j * 16 + l15;
            float bn;
            if (MODE == 1) bn = (n < 768) ? bias0[n] : bias1[n - 768];
            else           bn = bias0[n];
            if (MODE == 1 && n >= 768) {
                const int m = m0 + wm * 64 + i * 16 + quad * 4;
                int b = m / (NA * NS);
                int rem = m - b * (NA * NS);
                int a = rem >> 10, s = rem & 1023;
                int hh = (n - 768) >> 6;
                bf16x4 pk;
#pragma unroll
                for (int rg = 0; rg < 4; rg++) pk[rg] = (bf16_t)(acc[i][j][rg] + bn);
                char* dst = (char*)out1 + (size_t)((b * NHEADS + hh) * NA + a) * 131072
                            + (size_t)(s >> 5) * 4096 + j * 1024
                            + (quad * 16 + l15) * 16 + (i & 1) * 8;
                *reinterpret_cast<bf16x4*>(dst) = pk;
            } else {
#pragma unroll
                for (int rg = 0; rg < 4; rg++) {
                    const int m = m0 + wm * 64 + i * 16 + quad * 4 + rg;
                    float v = acc[i][j][rg] + bn;
                    if (MODE == 0) {
                        int b = m >> 10, s = m & 1023, hh = n >> 6, d = n & 63;
                        out0[(((size_t)(b * NHEADS + hh) * NS) + s) * HD + d] = (bf16_t)v;
                    } else if (MODE == 1) {
                        int b = m / (NA * NS);
                        int rem = m - b * (NA * NS);
                        int a = rem >> 10, s = rem & 1023;
                        int hh = n >> 6, d = n & 63;
                        out0[((((size_t)(b * NHEADS + hh) * NA + a) * NS) + s) * HD + d] = (bf16_t)v;
                    } else {
                        v += resid[(size_t)m * NHID + n];
                        outf[(size_t)m * NHID + n] = v;
                    }
                }
            }
        }
    }
}

// ---------------------------------------------------------------------------
// Attention R17: block = 2 waves x 32 q-rows/wave (64 q-rows/block, same
// 768-block grid & LDS layout). Each wave amortizes every K/V LDS fragment
// over TWO 16-row q-tiles -> per-CU ds_read_b128 traffic HALVES (attn was
// LDS-read-bound: 288 reads/iter/CU ~ 3456 cyc vs ~350 cyc MFMA). Staging:
// 12 gl_lds16 per wave (uniform stride 4096B, loff = g*1024). Counted
// vmcnt(12) + 2 raw barriers (R15 discipline). LDS 48KB => 3 blocks/CU.
// ---------------------------------------------------------------------------
__global__ __launch_bounds__(128, 2) void attn_kernel(
    const bf16_t* __restrict__ Q, const bf16_t* __restrict__ K,
    const bf16_t* __restrict__ VT, bf16_t* __restrict__ AT)
{
    __shared__ __align__(16) char kv[2 * 24576];        // 2 x (K 12K + V 12K)

    const int t    = threadIdx.x;
    const int w    = t >> 6, lane = t & 63;
    const int quad = lane >> 4, l15 = lane & 15;

    int bh, qb;
    if (gridDim.x == 768) {           // full launch: XCD-local bh
        int xcd = blockIdx.x & 7, j = blockIdx.x >> 3;
        bh = (j >> 4) * 8 + xcd;      // 6 slabs x 8 xcd = 48
        qb = j & 15;                  // 16 blocks of 64 q-rows
    } else {                          // per-batch fallback (192 blocks)
        bh = blockIdx.x >> 4;
        qb = blockIdx.x & 15;
    }
    const int b  = bh / NHEADS, h = bh - b * NHEADS;
    const int q0 = qb * 64 + w * 32;  // wave's 32 q-rows (2 tiles of 16)

    const bf16_t* Qb = Q + ((size_t)bh * NS + q0) * HD;
    bf16x8 qf0[2], qf1[2];
#pragma unroll
    for (int t2 = 0; t2 < 2; t2++) {
        qf0[t2] = load8(Qb + (t2 * 16 + l15) * HD + quad * 8);
        qf1[t2] = load8(Qb + (t2 * 16 + l15) * HD + quad * 8 + 32);
    }

    // staging: 12 groups per wave (24 total: 12 K + 12 V); all strides 4096B
    const char* gp[12];
#pragma unroll
    for (int i = 0; i < 12; i++) {
        int g = w * 12 + i;
        if (g < 12) {   // K: a|j|dh
            int a = g >> 2, j = (g >> 1) & 1, dh = g & 1;
            gp[i] = (const char*)(K + ((size_t)(bh * NA + a) * NS + j * 16 + l15) * HD
                                  + dh * 32 + quad * 8);
        } else {        // Vp: a|dt -- contiguous 1KB per instr
            int gi = g - 12;
            int a = gi >> 2, dt = gi & 3;
            gp[i] = (const char*)VT + (size_t)(bh * NA + a) * 131072
                    + dt * 1024 + (size_t)lane * 16;
        }
    }

    auto stage = [&](int buf) {
#pragma unroll
        for (int i = 0; i < 12; i++) {
            gl_lds16(gp[i], kv + buf * 24576 + (w * 12 + i) * 1024);
            gp[i] += 4096;
        }
    };

    f32x4 acc[2][4];
#pragma unroll
    for (int t2 = 0; t2 < 2; t2++)
#pragma unroll
        for (int dt = 0; dt < 4; dt++) acc[t2][dt] = 0.0f;

    const float KS = 0.18033688011112042f;  // (1/8) * log2(e)

    stage(0);

    for (int it = 0; it < 32; ++it) {
        if (it + 1 < 32) {
            stage((it + 1) & 1);
            asm volatile("s_waitcnt vmcnt(12)" ::: "memory");  // stage(it) done
        } else {
            asm volatile("s_waitcnt vmcnt(0)" ::: "memory");
        }
        __builtin_amdgcn_s_barrier();

        const char* base = kv + (it & 1) * 24576;
        // swapped QK^T: K frags read ONCE, applied to both q-tiles
        f32x4 sc[2][3][2];
#pragma unroll
        for (int a = 0; a < 3; a++) {
#pragma unroll
            for (int j = 0; j < 2; j++) {
                bf16x8 klo = *(const bf16x8*)(base + ((a * 4 + j * 2 + 0) * 64 + lane) * 16);
                bf16x8 khi = *(const bf16x8*)(base + ((a * 4 + j * 2 + 1) * 64 + lane) * 16);
#pragma unroll
                for (int t2 = 0; t2 < 2; t2++) {
                    f32x4 z = 0.0f;
                    f32x4 c0 = MFMA(klo, qf0[t2], z);
                    sc[t2][a][j] = MFMA(khi, qf1[t2], c0);
                }
            }
        }
        // 3-exp softmax over adapters, fully in-register, per q-tile
        f32x4 plo[2][3], phi[2][3];
#pragma unroll
        for (int t2 = 0; t2 < 2; t2++) {
#pragma unroll
            for (int j = 0; j < 2; j++) {
#pragma unroll
                for (int rg = 0; rg < 4; rg++) {
                    float x0 = sc[t2][0][j][rg], x1 = sc[t2][1][j][rg], x2 = sc[t2][2][j][rg];
                    float mx = fmaxf(x0, fmaxf(x1, x2));
                    float e0 = __builtin_amdgcn_exp2f((x0 - mx) * KS);
                    float e1 = __builtin_amdgcn_exp2f((x1 - mx) * KS);
                    float e2 = __builtin_amdgcn_exp2f((x2 - mx) * KS);
                    float inv = __builtin_amdgcn_rcpf(e0 + e1 + e2);
                    if (j == 0) {
                        plo[t2][0][rg] = e0 * inv; plo[t2][1][rg] = e1 * inv; plo[t2][2][rg] = e2 * inv;
                    } else {
                        phi[t2][0][rg] = e0 * inv; phi[t2][1][rg] = e1 * inv; phi[t2][2][rg] = e2 * inv;
                    }
                }
            }
        }
        // PV: V frags read ONCE, applied to both q-tiles
#pragma unroll
        for (int a = 0; a < 3; a++) {
            bf16x8 pf0 = cvt8(plo[0][a], phi[0][a]);
            bf16x8 pf1 = cvt8(plo[1][a], phi[1][a]);
#pragma unroll
            for (int dt = 0; dt < 4; dt++) {
                bf16x8 vf = *(const bf16x8*)(base + 12288 + ((a * 4 + dt) * 64 + lane) * 16);
                acc[0][dt] = MFMA(pf0, vf, acc[0][dt]);
                acc[1][dt] = MFMA(pf1, vf, acc[1][dt]);
            }
        }
        __builtin_amdgcn_s_barrier();  // raw: guards buffer reuse
    }

    bf16_t* Ob = AT + (size_t)b * NS * NHID;
#pragma unroll
    for (int t2 = 0; t2 < 2; t2++) {
#pragma unroll
        for (int dt = 0; dt < 4; dt++) {
#pragma unroll
            for (int rg = 0; rg < 4; rg++) {
                int qq = q0 + t2 * 16 + quad * 4 + rg;
                Ob[(size_t)qq * NHID + h * HD + dt * 16 + l15] = (bf16_t)acc[t2][dt][rg];
            }
        }
    }
}

// ---------------------------------------------------------------------------
// LayerNorm over rows of X (fp32, [4096,768]), IN PLACE.
// R17: also fills its 1024-float slice of avg_weights (=1/3) -- absorbs the
// former fill_third launch (out1 scratch is dead by the time ln runs).
// ---------------------------------------------------------------------------
__global__ __launch_bounds__(256) void ln_kernel(
    float* __restrict__ X, const float* __restrict__ gamma,
    const float* __restrict__ beta, float* __restrict__ avgw)
{
    const int row = blockIdx.x;
    const int t = threadIdx.x;
    float* x = X + (size_t)row * NHID;
    float v0 = x[t], v1 = x[t + 256], v2 = x[t + 512];
    float s  = v0 + v1 + v2;
    float s2 = v0 * v0 + v1 * v1 + v2 * v2;
#pragma unroll
    for (int off = 32; off > 0; off >>= 1) {
        s  += __shfl_down(s, off);
        s2 += __shfl_down(s2, off);
    }
    __shared__ float red[8];
    const int w = t >> 6, lane = t & 63;
    if (lane == 0) { red[w] = s; red[4 + w] = s2; }
    __syncthreads();
    s  = red[0] + red[1] + red[2] + red[3];
    s2 = red[4] + red[5] + red[6] + red[7];
    float mu  = s * (1.0f / NHID);
    float var = s2 * (1.0f / NHID) - mu * mu;
    float rs  = rsqrtf(fmaxf(var, 0.0f) + 1e-5f);
    x[t]       = (v0 - mu) * rs * gamma[t]       + beta[t];
    x[t + 256] = (v1 - mu) * rs * gamma[t + 256] + beta[t + 256];
    x[t + 512] = (v2 - mu) * rs * gamma[t + 512] + beta[t + 512];
    // avg_weights: 1/3 identically; each block owns 1024 floats
    f32x4 v3 = { 1.0f / 3.0f, 1.0f / 3.0f, 1.0f / 3.0f, 1.0f / 3.0f };
    reinterpret_cast<f32x4*>(avgw)[(size_t)row * 256 + t] = v3;
}

// ---------------------------------------------------------------------------
// out0 [0,12.58MB) fp32: O-proj X -> LN in place. out1: bf16 scratch.
// ws tier 1 (>=67,633,152 B): K 18.87 | Vp 18.87 | adaptb 18.87 | Wqb/Wkb/
// Wvb/Wob 1.18 ea | queryb 6.29 MB. tier 2 (>=37,748,736): K | Vp only.
// ---------------------------------------------------------------------------
extern "C" void kernel_launch(void* const* d_in, const int* in_sizes, int n_in,
                              void* d_out, int out_size, void* d_ws, size_t ws_size,
                              hipStream_t stream)
{
    (void)in_sizes; (void)n_in; (void)out_size;
    const float* query = (const float*)d_in[0];
    const float* adapt = (const float*)d_in[1];
    const float* Wq    = (const float*)d_in[2];
    const float* bq    = (const float*)d_in[3];
    const float* Wk    = (const float*)d_in[4];
    const float* bk    = (const float*)d_in[5];
    const float* Wv    = (const float*)d_in[6];
    const float* bv    = (const float*)d_in[7];
    const float* Wo    = (const float*)d_in[8];
    const float* bo    = (const float*)d_in[9];
    const float* gamma = (const float*)d_in[10];
    const float* beta  = (const float*)d_in[11];

    float*  out0  = (float*)d_out;            // 3,145,728 fp32
    float*  out1f = out0 + 3145728;           // 4,194,304 fp32
    bf16_t* out1b = (bf16_t*)out1f;

    dim3 blk(256);
    dim3 ablk(128);

    if (ws_size >= (size_t)67633152) {
        // ---- tier 1: full bf16 pipeline; gemm8 QKV + 2ph O-proj ----
        bf16_t* Kw  = (bf16_t*)d_ws;
        bf16_t* VTw = (bf16_t*)((char*)d_ws + 18874368);
        bf16_t* Adb = (bf16_t*)((char*)d_ws + 37748736);   // adapt bf16
        bf16_t* Wqb = (bf16_t*)((char*)d_ws + 56623104);
        bf16_t* Wkb = (bf16_t*)((char*)d_ws + 57802752);
        bf16_t* Wvb = (bf16_t*)((char*)d_ws + 58982400);
        bf16_t* Wob = (bf16_t*)((char*)d_ws + 60162048);
        bf16_t* Qcb = (bf16_t*)((char*)d_ws + 61341696);   // query bf16
        bf16_t* Qw  = out1b;
        bf16_t* ATw = out1b + 3145728;
        // bulk fp32->bf16: adapt 2304 | query 768 | Wq/Wk/Wv/Wo 144 each
        cvt6<<<dim3(3648), blk, 0, stream>>>(
            adapt, Adb, 2304, query, Qcb, 3072,
            Wq, Wqb, 3216, Wk, Wkb, 3360, Wv, Wvb, 3504, Wo, Wob, 3648);
        // merged QKV: 576 KV blocks (256x128) + 96 Q blocks
        gemm8<<<dim3(672), dim3(512), 0, stream>>>(
            Adb, Wkb, Wvb, bk, bv, Kw, VTw, Qcb, Wqb, bq, Qw);
        attn_kernel<<<dim3(768), ablk, 0, stream>>>(Qw, Kw, VTw, ATw);
        proj_gemm<3, 6, true, true><<<dim3(192), blk, 0, stream>>>(
            ATw, Wob, nullptr, bo, nullptr, query, nullptr, nullptr, out0);
    } else if (ws_size >= (size_t)37748736) {
        // ---- tier 2: bf16 B only (W's in out1 spare), fp32 A ----
        bf16_t* Kw  = (bf16_t*)d_ws;
        bf16_t* VTw = (bf16_t*)((char*)d_ws + 18874368);
        bf16_t* Qw  = out1b;
        bf16_t* ATw = out1b + 3145728;
        bf16_t* Wqb = out1b + 6291456;         // 4.19MB spare in out1
        bf16_t* Wkb = Wqb + 589824;
        bf16_t* Wvb = Wkb + 589824;
        cvt6<<<dim3(432), blk, 0, stream>>>(
            Wq, Wqb, 144, Wk, Wkb, 288, Wv, Wvb, 432,
            Wv, Wvb, 432, Wv, Wvb, 432, Wv, Wvb, 432);
        proj_gemm<0, 6, false, true><<<dim3(192), blk, 0, stream>>>(
            query, Wqb, nullptr, bq, nullptr, nullptr, Qw, nullptr, nullptr);
        proj_gemm<1, 12, false, true><<<dim3(1152), blk, 0, stream>>>(
            adapt, Wkb, Wvb, bk, bv, nullptr, Kw, VTw, nullptr);
        attn_kernel<<<dim3(768), ablk, 0, stream>>>(Qw, Kw, VTw, ATw);
        proj_gemm<3, 6, true, false><<<dim3(192), blk, 0, stream>>>(
            ATw, Wo, nullptr, bo, nullptr, query, nullptr, nullptr, out0);
    } else {
        // per-batch, zero-workspace fallback (scratch inside out1)
        bf16_t* Qc  = out1b;                  //   786,432 bf16
        bf16_t* ATc = out1b + 786432;         //   786,432 bf16
        bf16_t* Kc  = out1b + 1572864;        // 2,359,296 bf16
        bf16_t* VTc = out1b + 3932160;        // 2,359,296 bf16
        for (int b = 0; b < NB; b++) {
            const float* qb = query + (size_t)b * NS * NHID;
            const float* ab = adapt + (size_t)b * NA * NS * NHID;
            proj_gemm<0, 6, false, false><<<dim3(48), blk, 0, stream>>>(
                qb, Wq, nullptr, bq, nullptr, nullptr, Qc, nullptr, nullptr);
            proj_gemm<1, 12, false, false><<<dim3(288), blk, 0, stream>>>(
                ab, Wk, Wv, bk, bv, nullptr, Kc, VTc, nullptr);
            attn_kernel<<<dim3(192), ablk, 0, stream>>>(Qc, Kc, VTc, ATc);
            proj_gemm<3, 6, true, false><<<dim3(48), blk, 0, stream>>>(
                ATc, Wo, nullptr, bo, nullptr, qb, nullptr, nullptr,
                out0 + (size_t)b * NS * NHID);
        }
    }

    ln_kernel<<<dim3(4096), blk, 0, stream>>>(out0, gamma, beta, out1f);
}

// Round 8
// 296.812 us; speedup vs baseline: 1.0065x; 1.0065x over previous
//
#include <hip/hip_runtime.h>

// Problem constants
#define NB 4
#define NA 3
#define NS 1024
#define NHID 768
#define NHEADS 12
#define HD 64

// (1/8) * log2(e): folded into Q at the producer; softmax uses exp2(x-mx).
#define QSCALE 0.18033688011112042f

typedef __bf16 bf16_t;
typedef __bf16 bf16x8 __attribute__((ext_vector_type(8)));
typedef __bf16 bf16x4 __attribute__((ext_vector_type(4)));
typedef float f32x4 __attribute__((ext_vector_type(4)));

#define MFMA(a, b, c) __builtin_amdgcn_mfma_f32_16x16x32_bf16(a, b, c, 0, 0, 0)

static __device__ __forceinline__ bf16x8 load8(const bf16_t* p) {
    return *reinterpret_cast<const bf16x8*>(p);
}

// async global->LDS, 16B per lane. LDS dest = wave-uniform base + lane*16.
typedef __attribute__((address_space(3))) unsigned int u32_lds;
typedef __attribute__((address_space(1))) unsigned int u32_glb;
static __device__ __forceinline__ void gl_lds16(const void* g, void* lds_base_uniform) {
    __builtin_amdgcn_global_load_lds((const u32_glb*)g, (u32_lds*)lds_base_uniform, 16, 0, 0);
}

static __device__ __forceinline__ bf16x8 cvt8(f32x4 lo, f32x4 hi) {
    bf16x8 r;
    r[0] = (bf16_t)lo[0]; r[1] = (bf16_t)lo[1]; r[2] = (bf16_t)lo[2]; r[3] = (bf16_t)lo[3];
    r[4] = (bf16_t)hi[0]; r[5] = (bf16_t)hi[1]; r[6] = (bf16_t)hi[2]; r[7] = (bf16_t)hi[3];
    return r;
}

// ---------------------------------------------------------------------------
// Vp layout (validated R14/R15): per (bh,a): 32 sb-blocks of 4KB:
//   byte = (bh*NA+a)*131072 + sb*4096 + dt*1024 + (q*16 + l)*16 + e*2
// holding V[d = dt*16+l][s = sb*32 + s5] with s5 = (e>>2)*16 + q*4 + (e&3).
// ---------------------------------------------------------------------------

// ---------------------------------------------------------------------------
// fp32 -> bf16 bulk conversion, up to 6 segments.
// ---------------------------------------------------------------------------
__global__ __launch_bounds__(256) void cvt6(
    const float* __restrict__ s0, bf16_t* __restrict__ d0, int c0,
    const float* __restrict__ s1, bf16_t* __restrict__ d1, int c1,
    const float* __restrict__ s2, bf16_t* __restrict__ d2, int c2,
    const float* __restrict__ s3, bf16_t* __restrict__ d3, int c3,
    const float* __restrict__ s4, bf16_t* __restrict__ d4, int c4,
    const float* __restrict__ s5, bf16_t* __restrict__ d5, int c5)
{
    const int bid = blockIdx.x;
    const float* s; bf16_t* d; int rel;
    if      (bid < c0) { s = s0; d = d0; rel = bid; }
    else if (bid < c1) { s = s1; d = d1; rel = bid - c0; }
    else if (bid < c2) { s = s2; d = d2; rel = bid - c1; }
    else if (bid < c3) { s = s3; d = d3; rel = bid - c2; }
    else if (bid < c4) { s = s4; d = d4; rel = bid - c3; }
    else               { s = s5; d = d5; rel = bid - c4; }
    const int t = threadIdx.x;
#pragma unroll
    for (int k = 0; k < 4; k++) {
        size_t u = (size_t)rel * 1024 + k * 256 + t;   // f32x4 unit index
        f32x4 v = reinterpret_cast<const f32x4*>(s)[u];
        bf16x4 o;
        o[0] = (bf16_t)v[0]; o[1] = (bf16_t)v[1];
        o[2] = (bf16_t)v[2]; o[3] = (bf16_t)v[3];
        reinterpret_cast<bf16x4*>(d)[u] = o;
    }
}

// ---------------------------------------------------------------------------
// R16 gemm8: 256x128 tile, BK=64, 8 waves, 3-buf depth-2 counted-vmcnt,
// 2 phases/iter with setprio. Blocks [0,576): KV. [576,672): Q.
// R18: Q epilogue pre-scales by QSCALE (folds softmax scale into Q).
// ---------------------------------------------------------------------------
__global__ __launch_bounds__(512) void gemm8(
    const bf16_t* __restrict__ X,
    const bf16_t* __restrict__ W0, const bf16_t* __restrict__ W1,
    const float* __restrict__ bias0, const float* __restrict__ bias1,
    bf16_t* __restrict__ outK, bf16_t* __restrict__ outV,
    const bf16_t* __restrict__ X2, const bf16_t* __restrict__ W2,
    const float* __restrict__ bias2, bf16_t* __restrict__ outQ)
{
    constexpr int BUFSZ = 49152;                  // A 32K + B 16K
    __shared__ __align__(16) char smem[3 * BUFSZ];

    const int t = threadIdx.x;
    const int lane = t & 63, w = t >> 6;          // w in [0,8)
    const int quad = lane >> 4, l15 = lane & 15;
    const int wm = w >> 1, wn = w & 1;            // 4M x 2N wave grid

    int emode = 1, nt = 12, bid = blockIdx.x;
    const bf16_t* Xp = X;
    const bf16_t* Wp = W0;
    const float*  b0 = bias0;
    if (bid >= 576) {                             // Q region
        emode = 0; nt = 6; bid -= 576;
        Xp = X2; Wp = W2; b0 = bias2;
    }

    // XCD-aware swizzle
    const int xcd = bid & 7, jj = bid >> 3;
    const int n_t = jj % nt, slab = jj / nt;
    const int m0 = (slab * 8 + xcd) * 256;
    const int n0 = n_t * 128;

    const bf16_t* Wsel = (emode == 1 && n0 >= 768) ? W1 : Wp;
    const int n0b = (emode == 1 && n0 >= 768) ? n0 - 768 : n0;

    const bf16_t* sp[6];
    int loff[6];
#pragma unroll
    for (int i = 0; i < 6; i++) {
        int g = w * 6 + i;
        loff[i] = g * 1024;
        if (g < 32) {
            int ks = g >> 4, mt = g & 15;
            sp[i] = Xp + (size_t)(m0 + mt * 16 + l15) * NHID + ks * 32 + quad * 8;
        } else {
            int gb = g - 32;
            int ks = gb >> 3, ntile = gb & 7;
            sp[i] = Wsel + (size_t)(n0b + ntile * 16 + l15) * NHID + ks * 32 + quad * 8;
        }
    }

    auto stage_half = [&](char* base, int h) {     // 3 instrs per half
#pragma unroll
        for (int i = 0; i < 3; i++) {
            int idx = h * 3 + i;
            gl_lds16(sp[idx], base + loff[idx]);
            sp[idx] += 64;                         // BK=64 elements
        }
    };

    f32x4 acc[4][4];
#pragma unroll
    for (int i = 0; i < 4; i++)
#pragma unroll
        for (int j = 0; j < 4; j++) acc[i][j] = 0.0f;

    constexpr int KITER = NHID / 64;               // 12
    stage_half(smem, 0);          stage_half(smem, 1);           // stage(0)
    stage_half(smem + BUFSZ, 0);  stage_half(smem + BUFSZ, 1);   // stage(1)

    for (int it = 0; it < KITER; ++it) {
        if (it == KITER - 1) asm volatile("s_waitcnt vmcnt(0)" ::: "memory");
        else                 asm volatile("s_waitcnt vmcnt(6)" ::: "memory");
        __builtin_amdgcn_s_barrier();              // all waves' stage(it) done

        const char* rb = smem + (it % 3) * BUFSZ;
        char* pb = smem + ((it + 2) % 3) * BUFSZ;
        const bool dostage = (it + 2 < KITER);

#pragma unroll
        for (int ks = 0; ks < 2; ++ks) {           // 2 phases per iteration
            bf16x8 af[4], bfr[4];
#pragma unroll
            for (int i = 0; i < 4; i++)
                af[i] = *(const bf16x8*)(rb + (ks * 16 + wm * 4 + i) * 1024 + lane * 16);
#pragma unroll
            for (int j = 0; j < 4; j++)
                bfr[j] = *(const bf16x8*)(rb + 32768 + (ks * 8 + wn * 4 + j) * 1024 + lane * 16);
            if (dostage) stage_half(pb, ks);
            __builtin_amdgcn_s_setprio(1);
#pragma unroll
            for (int i = 0; i < 4; i++)
#pragma unroll
                for (int j = 0; j < 4; j++)
                    acc[i][j] = MFMA(af[i], bfr[j], acc[i][j]);
            __builtin_amdgcn_s_setprio(0);
            if (ks == 0) __builtin_amdgcn_s_barrier();   // phase boundary
        }
    }

    // ---- epilogue: per-wave 64x64 at (m0 + wm*64, n0 + wn*64) ----
#pragma unroll
    for (int i = 0; i < 4; i++) {
#pragma unroll
        for (int j = 0; j < 4; j++) {
            const int n = n0 + wn * 64 + j * 16 + l15;
            float bn;
            if (emode == 1) bn = (n < 768) ? b0[n] : bias1[n - 768];
            else            bn = b0[n];
            if (emode == 1 && n >= 768) {
                // Vp layout, bf16x4-packed (rg -> consecutive e-slots)
                const int m = m0 + wm * 64 + i * 16 + quad * 4;
                int b = m / (NA * NS);
                int rem = m - b * (NA * NS);
                int a = rem >> 10, s = rem & 1023;
                int hh = (n - 768) >> 6;
                bf16x4 pk;
#pragma unroll
                for (int rg = 0; rg < 4; rg++) pk[rg] = (bf16_t)(acc[i][j][rg] + bn);
                char* dst = (char*)outV + (size_t)((b * NHEADS + hh) * NA + a) * 131072
                            + (size_t)(s >> 5) * 4096 + j * 1024
                            + (quad * 16 + l15) * 16 + (i & 1) * 8;
                *reinterpret_cast<bf16x4*>(dst) = pk;
            } else {
#pragma unroll
                for (int rg = 0; rg < 4; rg++) {
                    const int m = m0 + wm * 64 + i * 16 + quad * 4 + rg;
                    float v = acc[i][j][rg] + bn;
                    if (emode == 0) {
                        v *= QSCALE;   // fold softmax scale into Q
                        int b = m >> 10, s = m & 1023, hh = n >> 6, d = n & 63;
                        outQ[(((size_t)(b * NHEADS + hh) * NS) + s) * HD + d] = (bf16_t)v;
                    } else {
                        int b = m / (NA * NS);
                        int rem = m - b * (NA * NS);
                        int a = rem >> 10, s = rem & 1023;
                        int hh = n >> 6, d = n & 63;
                        outK[((((size_t)(b * NHEADS + hh) * NA + a) * NS) + s) * HD + d] = (bf16_t)v;
                    }
                }
            }
        }
    }
}

// ---------------------------------------------------------------------------
// Projection GEMM (R15 structure), used for O-proj and tiers 2/3.
// 128x128 tile, BK=32, 4 waves, 2 buffers + 2 raw barriers + counted vmcnt.
// R18: MODE 0 epilogue pre-scales by QSCALE.
// ---------------------------------------------------------------------------
template <int MODE, int NT, bool ABF, bool BBF>
__global__ __launch_bounds__(256) void proj_gemm(
    const void* __restrict__ Xv,
    const void* __restrict__ W0v, const void* __restrict__ W1v,
    const float* __restrict__ bias0, const float* __restrict__ bias1,
    const float* __restrict__ resid,
    bf16_t* __restrict__ out0, bf16_t* __restrict__ out1,
    float* __restrict__ outf)
{
    constexpr int ASZ   = ABF ? 8192 : 16384;
    constexpr int BSZ   = BBF ? 8192 : 16384;
    constexpr int BUFSZ = ASZ + BSZ;
    constexpr int LPS   = (ABF ? 2 : 4) + (BBF ? 2 : 4);
    __shared__ __align__(16) char smem[2 * BUFSZ];

    const int t = threadIdx.x;
    const int lane = t & 63, w = t >> 6;
    const int quad = lane >> 4, l15 = lane & 15;
    const int wm = w >> 1, wn = w & 1;

    const int bid = blockIdx.x;
    const int xcd = bid & 7, jj = bid >> 3;
    const int n_t = jj % NT, slab = jj / NT;
    const int m0 = (slab * 8 + xcd) * 128;
    const int n0 = n_t * 128;

    const void* Wselv = (MODE == 1 && n0 >= 768) ? W1v : W0v;
    const int n0b = (MODE == 1 && n0 >= 768) ? n0 - 768 : n0;

    const int srow  = lane >> 3;
    const int schnk = (lane & 7) ^ srow;
    const float*  Apf[4];
    const bf16_t* Apb[2];
    const float*  Bpf[4];
    const bf16_t* Bpb[2];
    if constexpr (ABF) {
        const bf16_t* X = (const bf16_t*)Xv;
#pragma unroll
        for (int i = 0; i < 2; i++) {
            int g = w * 2 + i;
            Apb[i] = X + (size_t)(m0 + g * 16 + l15) * NHID + quad * 8;
        }
    } else {
        const float* X = (const float*)Xv;
#pragma unroll
        for (int i = 0; i < 4; i++) {
            int g = w * 4 + i;
            Apf[i] = X + (size_t)(m0 + g * 8 + srow) * NHID + schnk * 4;
        }
    }
    if constexpr (BBF) {
        const bf16_t* Wb = (const bf16_t*)Wselv;
#pragma unroll
        for (int i = 0; i < 2; i++) {
            int g = w * 2 + i;
            Bpb[i] = Wb + (size_t)(n0b + g * 16 + l15) * NHID + quad * 8;
        }
    } else {
        const float* Wf = (const float*)Wselv;
#pragma unroll
        for (int i = 0; i < 4; i++) {
            int g = w * 4 + i;
            Bpf[i] = Wf + (size_t)(n0b + g * 8 + srow) * NHID + schnk * 4;
        }
    }

    auto stage = [&](char* base) {
        char* Ab = base;
        char* Bb = base + ASZ;
        if constexpr (ABF) {
#pragma unroll
            for (int i = 0; i < 2; i++) { gl_lds16(Apb[i], Ab + (w * 2 + i) * 1024); Apb[i] += 32; }
        } else {
#pragma unroll
            for (int i = 0; i < 4; i++) { gl_lds16(Apf[i], Ab + (w * 4 + i) * 1024); Apf[i] += 32; }
        }
        if constexpr (BBF) {
#pragma unroll
            for (int i = 0; i < 2; i++) { gl_lds16(Bpb[i], Bb + (w * 2 + i) * 1024); Bpb[i] += 32; }
        } else {
#pragma unroll
            for (int i = 0; i < 4; i++) { gl_lds16(Bpf[i], Bb + (w * 4 + i) * 1024); Bpf[i] += 32; }
        }
    };

    auto wait_one = [&]() {
        if constexpr (LPS == 4)      asm volatile("s_waitcnt vmcnt(4)" ::: "memory");
        else if constexpr (LPS == 6) asm volatile("s_waitcnt vmcnt(6)" ::: "memory");
        else                         asm volatile("s_waitcnt vmcnt(8)" ::: "memory");
    };

    f32x4 acc[4][4];
#pragma unroll
    for (int i = 0; i < 4; i++)
#pragma unroll
        for (int j = 0; j < 4; j++) acc[i][j] = 0.0f;

    constexpr int KITER = NHID / 32;   // 24
    stage(smem);

    for (int it = 0; it < KITER; ++it) {
        if (it + 1 < KITER) {
            stage(smem + ((it + 1) & 1) * BUFSZ);
            wait_one();
        } else {
            asm volatile("s_waitcnt vmcnt(0)" ::: "memory");
        }
        __builtin_amdgcn_s_barrier();

        char* Ab = smem + (it & 1) * BUFSZ;
        char* Bb = Ab + ASZ;

        bf16x8 af[4], bfr[4];
        const int pl = (2 * quad) ^ (l15 & 7);
#pragma unroll
        for (int i = 0; i < 4; i++) {
            if constexpr (ABF) {
                int mt = wm * 4 + i;
                af[i] = *(const bf16x8*)(Ab + (mt * 64 + lane) * 16);
            } else {
                int R = (wm * 4 + i) * 16 + l15;
                f32x4 lo = *(const f32x4*)(Ab + R * 128 + pl * 16);
                f32x4 hi = *(const f32x4*)(Ab + R * 128 + (pl ^ 1) * 16);
                af[i] = cvt8(lo, hi);
            }
        }
#pragma unroll
        for (int j = 0; j < 4; j++) {
            if constexpr (BBF) {
                int ntj = wn * 4 + j;
                bfr[j] = *(const bf16x8*)(Bb + (ntj * 64 + lane) * 16);
            } else {
                int R = (wn * 4 + j) * 16 + l15;
                f32x4 lo = *(const f32x4*)(Bb + R * 128 + pl * 16);
                f32x4 hi = *(const f32x4*)(Bb + R * 128 + (pl ^ 1) * 16);
                bfr[j] = cvt8(lo, hi);
            }
        }
#pragma unroll
        for (int i = 0; i < 4; i++)
#pragma unroll
            for (int j = 0; j < 4; j++)
                acc[i][j] = MFMA(af[i], bfr[j], acc[i][j]);
        __builtin_amdgcn_s_barrier();
    }

#pragma unroll
    for (int i = 0; i < 4; i++) {
#pragma unroll
        for (int j = 0; j < 4; j++) {
            const int n = n0 + wn * 64 + j * 16 + l15;
            float bn;
            if (MODE == 1) bn = (n < 768) ? bias0[n] : bias1[n - 768];
            else           bn = bias0[n];
            if (MODE == 1 && n >= 768) {
                const int m = m0 + wm * 64 + i * 16 + quad * 4;
                int b = m / (NA * NS);
                int rem = m - b * (NA * NS);
                int a = rem >> 10, s = rem & 1023;
                int hh = (n - 768) >> 6;
                bf16x4 pk;
#pragma unroll
                for (int rg = 0; rg < 4; rg++) pk[rg] = (bf16_t)(acc[i][j][rg] + bn);
                char* dst = (char*)out1 + (size_t)((b * NHEADS + hh) * NA + a) * 131072
                            + (size_t)(s >> 5) * 4096 + j * 1024
                            + (quad * 16 + l15) * 16 + (i & 1) * 8;
                *reinterpret_cast<bf16x4*>(dst) = pk;
            } else {
#pragma unroll
                for (int rg = 0; rg < 4; rg++) {
                    const int m = m0 + wm * 64 + i * 16 + quad * 4 + rg;
                    float v = acc[i][j][rg] + bn;
                    if (MODE == 0) {
                        v *= QSCALE;   // fold softmax scale into Q
                        int b = m >> 10, s = m & 1023, hh = n >> 6, d = n & 63;
                        out0[(((size_t)(b * NHEADS + hh) * NS) + s) * HD + d] = (bf16_t)v;
                    } else if (MODE == 1) {
                        int b = m / (NA * NS);
                        int rem = m - b * (NA * NS);
                        int a = rem >> 10, s = rem & 1023;
                        int hh = n >> 6, d = n & 63;
                        out0[((((size_t)(b * NHEADS + hh) * NA + a) * NS) + s) * HD + d] = (bf16_t)v;
                    } else {
                        v += resid[(size_t)m * NHID + n];
                        outf[(size_t)m * NHID + n] = v;
                    }
                }
            }
        }
    }
}

// ---------------------------------------------------------------------------
// Attention R18: block = 4 waves x 32 q-rows/wave = 128 q-rows/block,
// grid 384 (48 bh x 8 qb, XCD-local bh). Combines R17's 2-q-tile/wave K/V
// amortization (per-work LDS reads halved) with R15's 4-wave occupancy:
// 3 blocks/CU = 12 waves/CU (R17's 128-thr blocks starved the VALU pipe at
// ~1 wave/SIMD; softmax is VALU-bound). Staging identical to R15: 24 groups
// (6/wave), vmcnt(6), 2 raw barriers. Q arrives pre-scaled by QSCALE.
// ---------------------------------------------------------------------------
__global__ __launch_bounds__(256, 3) void attn_kernel(
    const bf16_t* __restrict__ Q, const bf16_t* __restrict__ K,
    const bf16_t* __restrict__ VT, bf16_t* __restrict__ AT)
{
    __shared__ __align__(16) char kv[2 * 24576];        // 2 x (K 12K + V 12K)

    const int t    = threadIdx.x;
    const int w    = t >> 6, lane = t & 63;
    const int quad = lane >> 4, l15 = lane & 15;

    int bh, qb;
    if (gridDim.x == 384) {           // full launch: XCD-local bh
        int xcd = blockIdx.x & 7, j = blockIdx.x >> 3;
        bh = (j >> 3) * 8 + xcd;      // 6 slabs x 8 xcd = 48
        qb = j & 7;                   // 8 blocks of 128 q-rows
    } else {                          // per-batch fallback (96 blocks)
        bh = blockIdx.x >> 3;
        qb = blockIdx.x & 7;
    }
    const int b  = bh / NHEADS, h = bh - b * NHEADS;
    const int q0 = qb * 128 + w * 32;  // wave's 32 q-rows (2 tiles of 16)

    const bf16_t* Qb = Q + ((size_t)bh * NS + q0) * HD;
    bf16x8 qf0[2], qf1[2];
#pragma unroll
    for (int t2 = 0; t2 < 2; t2++) {
        qf0[t2] = load8(Qb + (t2 * 16 + l15) * HD + quad * 8);
        qf1[t2] = load8(Qb + (t2 * 16 + l15) * HD + quad * 8 + 32);
    }

    // staging: 6 groups per wave (24 total: 12 K + 12 V); all strides 4096B
    const char* gp[6];
    int loff[6];
#pragma unroll
    for (int i = 0; i < 6; i++) {
        int g = w * 6 + i;
        loff[i] = g >= 12 ? 12288 + (g - 12) * 1024 : g * 1024;
        if (g < 12) {   // K: a|j|dh
            int a = g >> 2, j = (g >> 1) & 1, dh = g & 1;
            gp[i] = (const char*)(K + ((size_t)(bh * NA + a) * NS + j * 16 + l15) * HD
                                  + dh * 32 + quad * 8);
        } else {        // Vp: a|dt -- contiguous 1KB per instr
            int gi = g - 12;
            int a = gi >> 2, dt = gi & 3;
            gp[i] = (const char*)VT + (size_t)(bh * NA + a) * 131072
                    + dt * 1024 + (size_t)lane * 16;
        }
    }

    auto stage = [&](int buf) {
#pragma unroll
        for (int i = 0; i < 6; i++) {
            gl_lds16(gp[i], kv + buf * 24576 + loff[i]);
            gp[i] += 4096;
        }
    };

    f32x4 acc[2][4];
#pragma unroll
    for (int t2 = 0; t2 < 2; t2++)
#pragma unroll
        for (int dt = 0; dt < 4; dt++) acc[t2][dt] = 0.0f;

    stage(0);

    for (int it = 0; it < 32; ++it) {
        if (it + 1 < 32) {
            stage((it + 1) & 1);
            asm volatile("s_waitcnt vmcnt(6)" ::: "memory");  // stage(it) done
        } else {
            asm volatile("s_waitcnt vmcnt(0)" ::: "memory");
        }
        __builtin_amdgcn_s_barrier();

        const char* base = kv + (it & 1) * 24576;
        // swapped QK^T: K frags read ONCE, applied to both q-tiles
        f32x4 sc[2][3][2];
#pragma unroll
        for (int a = 0; a < 3; a++) {
#pragma unroll
            for (int j = 0; j < 2; j++) {
                bf16x8 klo = *(const bf16x8*)(base + ((a * 4 + j * 2 + 0) * 64 + lane) * 16);
                bf16x8 khi = *(const bf16x8*)(base + ((a * 4 + j * 2 + 1) * 64 + lane) * 16);
#pragma unroll
                for (int t2 = 0; t2 < 2; t2++) {
                    f32x4 z = 0.0f;
                    f32x4 c0 = MFMA(klo, qf0[t2], z);
                    sc[t2][a][j] = MFMA(khi, qf1[t2], c0);
                }
            }
        }
        // 3-exp softmax over adapters (Q pre-scaled: exp2(x-mx) direct)
        f32x4 plo[2][3], phi[2][3];
#pragma unroll
        for (int t2 = 0; t2 < 2; t2++) {
#pragma unroll
            for (int j = 0; j < 2; j++) {
#pragma unroll
                for (int rg = 0; rg < 4; rg++) {
                    float x0 = sc[t2][0][j][rg], x1 = sc[t2][1][j][rg], x2 = sc[t2][2][j][rg];
                    float mx = fmaxf(x0, fmaxf(x1, x2));
                    float e0 = __builtin_amdgcn_exp2f(x0 - mx);
                    float e1 = __builtin_amdgcn_exp2f(x1 - mx);
                    float e2 = __builtin_amdgcn_exp2f(x2 - mx);
                    float inv = __builtin_amdgcn_rcpf(e0 + e1 + e2);
                    if (j == 0) {
                        plo[t2][0][rg] = e0 * inv; plo[t2][1][rg] = e1 * inv; plo[t2][2][rg] = e2 * inv;
                    } else {
                        phi[t2][0][rg] = e0 * inv; phi[t2][1][rg] = e1 * inv; phi[t2][2][rg] = e2 * inv;
                    }
                }
            }
        }
        // PV: V frags read ONCE, applied to both q-tiles
#pragma unroll
        for (int a = 0; a < 3; a++) {
            bf16x8 pf0 = cvt8(plo[0][a], phi[0][a]);
            bf16x8 pf1 = cvt8(plo[1][a], phi[1][a]);
#pragma unroll
            for (int dt = 0; dt < 4; dt++) {
                bf16x8 vf = *(const bf16x8*)(base + 12288 + ((a * 4 + dt) * 64 + lane) * 16);
                acc[0][dt] = MFMA(pf0, vf, acc[0][dt]);
                acc[1][dt] = MFMA(pf1, vf, acc[1][dt]);
            }
        }
        __builtin_amdgcn_s_barrier();  // raw: guards buffer reuse
    }

    bf16_t* Ob = AT + (size_t)b * NS * NHID;
#pragma unroll
    for (int t2 = 0; t2 < 2; t2++) {
#pragma unroll
        for (int dt = 0; dt < 4; dt++) {
#pragma unroll
            for (int rg = 0; rg < 4; rg++) {
                int qq = q0 + t2 * 16 + quad * 4 + rg;
                Ob[(size_t)qq * NHID + h * HD + dt * 16 + l15] = (bf16_t)acc[t2][dt][rg];
            }
        }
    }
}

// ---------------------------------------------------------------------------
// LayerNorm over rows of X (fp32, [4096,768]), IN PLACE. Also fills its
// 1024-float slice of avg_weights (=1/3).
// ---------------------------------------------------------------------------
__global__ __launch_bounds__(256) void ln_kernel(
    float* __restrict__ X, const float* __restrict__ gamma,
    const float* __restrict__ beta, float* __restrict__ avgw)
{
    const int row = blockIdx.x;
    const int t = threadIdx.x;
    float* x = X + (size_t)row * NHID;
    float v0 = x[t], v1 = x[t + 256], v2 = x[t + 512];
    float s  = v0 + v1 + v2;
    float s2 = v0 * v0 + v1 * v1 + v2 * v2;
#pragma unroll
    for (int off = 32; off > 0; off >>= 1) {
        s  += __shfl_down(s, off);
        s2 += __shfl_down(s2, off);
    }
    __shared__ float red[8];
    const int w = t >> 6, lane = t & 63;
    if (lane == 0) { red[w] = s; red[4 + w] = s2; }
    __syncthreads();
    s  = red[0] + red[1] + red[2] + red[3];
    s2 = red[4] + red[5] + red[6] + red[7];
    float mu  = s * (1.0f / NHID);
    float var = s2 * (1.0f / NHID) - mu * mu;
    float rs  = rsqrtf(fmaxf(var, 0.0f) + 1e-5f);
    x[t]       = (v0 - mu) * rs * gamma[t]       + beta[t];
    x[t + 256] = (v1 - mu) * rs * gamma[t + 256] + beta[t + 256];
    x[t + 512] = (v2 - mu) * rs * gamma[t + 512] + beta[t + 512];
    // avg_weights: 1/3 identically; each block owns 1024 floats
    f32x4 v3 = { 1.0f / 3.0f, 1.0f / 3.0f, 1.0f / 3.0f, 1.0f / 3.0f };
    reinterpret_cast<f32x4*>(avgw)[(size_t)row * 256 + t] = v3;
}

// ---------------------------------------------------------------------------
// out0 [0,12.58MB) fp32: O-proj X -> LN in place. out1: bf16 scratch.
// ws tier 1 (>=67,633,152 B): K 18.87 | Vp 18.87 | adaptb 18.87 | Wqb/Wkb/
// Wvb/Wob 1.18 ea | queryb 6.29 MB. tier 2 (>=37,748,736): K | Vp only.
// ---------------------------------------------------------------------------
extern "C" void kernel_launch(void* const* d_in, const int* in_sizes, int n_in,
                              void* d_out, int out_size, void* d_ws, size_t ws_size,
                              hipStream_t stream)
{
    (void)in_sizes; (void)n_in; (void)out_size;
    const float* query = (const float*)d_in[0];
    const float* adapt = (const float*)d_in[1];
    const float* Wq    = (const float*)d_in[2];
    const float* bq    = (const float*)d_in[3];
    const float* Wk    = (const float*)d_in[4];
    const float* bk    = (const float*)d_in[5];
    const float* Wv    = (const float*)d_in[6];
    const float* bv    = (const float*)d_in[7];
    const float* Wo    = (const float*)d_in[8];
    const float* bo    = (const float*)d_in[9];
    const float* gamma = (const float*)d_in[10];
    const float* beta  = (const float*)d_in[11];

    float*  out0  = (float*)d_out;            // 3,145,728 fp32
    float*  out1f = out0 + 3145728;           // 4,194,304 fp32
    bf16_t* out1b = (bf16_t*)out1f;

    dim3 blk(256);

    if (ws_size >= (size_t)67633152) {
        // ---- tier 1: full bf16 pipeline; gemm8 QKV + 2ph O-proj ----
        bf16_t* Kw  = (bf16_t*)d_ws;
        bf16_t* VTw = (bf16_t*)((char*)d_ws + 18874368);
        bf16_t* Adb = (bf16_t*)((char*)d_ws + 37748736);   // adapt bf16
        bf16_t* Wqb = (bf16_t*)((char*)d_ws + 56623104);
        bf16_t* Wkb = (bf16_t*)((char*)d_ws + 57802752);
        bf16_t* Wvb = (bf16_t*)((char*)d_ws + 58982400);
        bf16_t* Wob = (bf16_t*)((char*)d_ws + 60162048);
        bf16_t* Qcb = (bf16_t*)((char*)d_ws + 61341696);   // query bf16
        bf16_t* Qw  = out1b;
        bf16_t* ATw = out1b + 3145728;
        // bulk fp32->bf16: adapt 2304 | query 768 | Wq/Wk/Wv/Wo 144 each
        cvt6<<<dim3(3648), blk, 0, stream>>>(
            adapt, Adb, 2304, query, Qcb, 3072,
            Wq, Wqb, 3216, Wk, Wkb, 3360, Wv, Wvb, 3504, Wo, Wob, 3648);
        // merged QKV: 576 KV blocks (256x128) + 96 Q blocks
        gemm8<<<dim3(672), dim3(512), 0, stream>>>(
            Adb, Wkb, Wvb, bk, bv, Kw, VTw, Qcb, Wqb, bq, Qw);
        attn_kernel<<<dim3(384), blk, 0, stream>>>(Qw, Kw, VTw, ATw);
        proj_gemm<3, 6, true, true><<<dim3(192), blk, 0, stream>>>(
            ATw, Wob, nullptr, bo, nullptr, query, nullptr, nullptr, out0);
    } else if (ws_size >= (size_t)37748736) {
        // ---- tier 2: bf16 B only (W's in out1 spare), fp32 A ----
        bf16_t* Kw  = (bf16_t*)d_ws;
        bf16_t* VTw = (bf16_t*)((char*)d_ws + 18874368);
        bf16_t* Qw  = out1b;
        bf16_t* ATw = out1b + 3145728;
        bf16_t* Wqb = out1b + 6291456;         // 4.19MB spare in out1
        bf16_t* Wkb = Wqb + 589824;
        bf16_t* Wvb = Wkb + 589824;
        cvt6<<<dim3(432), blk, 0, stream>>>(
            Wq, Wqb, 144, Wk, Wkb, 288, Wv, Wvb, 432,
            Wv, Wvb, 432, Wv, Wvb, 432, Wv, Wvb, 432);
        proj_gemm<0, 6, false, true><<<dim3(192), blk, 0, stream>>>(
            query, Wqb, nullptr, bq, nullptr, nullptr, Qw, nullptr, nullptr);
        proj_gemm<1, 12, false, true><<<dim3(1152), blk, 0, stream>>>(
            adapt, Wkb, Wvb, bk, bv, nullptr, Kw, VTw, nullptr);
        attn_kernel<<<dim3(384), blk, 0, stream>>>(Qw, Kw, VTw, ATw);
        proj_gemm<3, 6, true, false><<<dim3(192), blk, 0, stream>>>(
            ATw, Wo, nullptr, bo, nullptr, query, nullptr, nullptr, out0);
    } else {
        // per-batch, zero-workspace fallback (scratch inside out1)
        bf16_t* Qc  = out1b;                  //   786,432 bf16
        bf16_t* ATc = out1b + 786432;         //   786,432 bf16
        bf16_t* Kc  = out1b + 1572864;        // 2,359,296 bf16
        bf16_t* VTc = out1b + 3932160;        // 2,359,296 bf16
        for (int b = 0; b < NB; b++) {
            const float* qb = query + (size_t)b * NS * NHID;
            const float* ab = adapt + (size_t)b * NA * NS * NHID;
            proj_gemm<0, 6, false, false><<<dim3(48), blk, 0, stream>>>(
                qb, Wq, nullptr, bq, nullptr, nullptr, Qc, nullptr, nullptr);
            proj_gemm<1, 12, false, false><<<dim3(288), blk, 0, stream>>>(
                ab, Wk, Wv, bk, bv, nullptr, Kc, VTc, nullptr);
            attn_kernel<<<dim3(96), blk, 0, stream>>>(Qc, Kc, VTc, ATc);
            proj_gemm<3, 6, true, false><<<dim3(48), blk, 0, stream>>>(
                ATc, Wo, nullptr, bo, nullptr, qb, nullptr, nullptr,
                out0 + (size_t)b * NS * NHID);
        }
    }

    ln_kernel<<<dim3(4096), blk, 0, stream>>>(out0, gamma, beta, out1f);
}

// Round 9
// 276.976 us; speedup vs baseline: 1.0786x; 1.0716x over previous
//
#include <hip/hip_runtime.h>

// Problem constants
#define NB 4
#define NA 3
#define NS 1024
#define NHID 768
#define NHEADS 12
#define HD 64

// (1/8) * log2(e): folded into Q at the producer; softmax uses exp2(x-mx).
#define QSCALE 0.18033688011112042f

typedef __bf16 bf16_t;
typedef __bf16 bf16x8 __attribute__((ext_vector_type(8)));
typedef __bf16 bf16x4 __attribute__((ext_vector_type(4)));
typedef float f32x4 __attribute__((ext_vector_type(4)));

#define MFMA(a, b, c) __builtin_amdgcn_mfma_f32_16x16x32_bf16(a, b, c, 0, 0, 0)

static __device__ __forceinline__ bf16x8 load8(const bf16_t* p) {
    return *reinterpret_cast<const bf16x8*>(p);
}

// async global->LDS, 16B per lane. LDS dest = wave-uniform base + lane*16.
typedef __attribute__((address_space(3))) unsigned int u32_lds;
typedef __attribute__((address_space(1))) unsigned int u32_glb;
static __device__ __forceinline__ void gl_lds16(const void* g, void* lds_base_uniform) {
    __builtin_amdgcn_global_load_lds((const u32_glb*)g, (u32_lds*)lds_base_uniform, 16, 0, 0);
}

static __device__ __forceinline__ bf16x8 cvt8(f32x4 lo, f32x4 hi) {
    bf16x8 r;
    r[0] = (bf16_t)lo[0]; r[1] = (bf16_t)lo[1]; r[2] = (bf16_t)lo[2]; r[3] = (bf16_t)lo[3];
    r[4] = (bf16_t)hi[0]; r[5] = (bf16_t)hi[1]; r[6] = (bf16_t)hi[2]; r[7] = (bf16_t)hi[3];
    return r;
}

// ---------------------------------------------------------------------------
// Vp layout (validated R14/R15): per (bh,a): 32 sb-blocks of 4KB:
//   byte = (bh*NA+a)*131072 + sb*4096 + dt*1024 + (q*16 + l)*16 + e*2
// holding V[d = dt*16+l][s = sb*32 + s5] with s5 = (e>>2)*16 + q*4 + (e&3).
// ---------------------------------------------------------------------------

// ---------------------------------------------------------------------------
// fp32 -> bf16 bulk conversion, up to 6 segments.
// ---------------------------------------------------------------------------
__global__ __launch_bounds__(256) void cvt6(
    const float* __restrict__ s0, bf16_t* __restrict__ d0, int c0,
    const float* __restrict__ s1, bf16_t* __restrict__ d1, int c1,
    const float* __restrict__ s2, bf16_t* __restrict__ d2, int c2,
    const float* __restrict__ s3, bf16_t* __restrict__ d3, int c3,
    const float* __restrict__ s4, bf16_t* __restrict__ d4, int c4,
    const float* __restrict__ s5, bf16_t* __restrict__ d5, int c5)
{
    const int bid = blockIdx.x;
    const float* s; bf16_t* d; int rel;
    if      (bid < c0) { s = s0; d = d0; rel = bid; }
    else if (bid < c1) { s = s1; d = d1; rel = bid - c0; }
    else if (bid < c2) { s = s2; d = d2; rel = bid - c1; }
    else if (bid < c3) { s = s3; d = d3; rel = bid - c2; }
    else if (bid < c4) { s = s4; d = d4; rel = bid - c3; }
    else               { s = s5; d = d5; rel = bid - c4; }
    const int t = threadIdx.x;
#pragma unroll
    for (int k = 0; k < 4; k++) {
        size_t u = (size_t)rel * 1024 + k * 256 + t;   // f32x4 unit index
        f32x4 v = reinterpret_cast<const f32x4*>(s)[u];
        bf16x4 o;
        o[0] = (bf16_t)v[0]; o[1] = (bf16_t)v[1];
        o[2] = (bf16_t)v[2]; o[3] = (bf16_t)v[3];
        reinterpret_cast<bf16x4*>(d)[u] = o;
    }
}

// ---------------------------------------------------------------------------
// R16 gemm8: 256x128 tile, BK=64, 8 waves, 3-buf depth-2 counted-vmcnt,
// 2 phases/iter with setprio. Blocks [0,576): KV. [576,672): Q.
// Q epilogue pre-scales by QSCALE (folds softmax scale into Q).
// ---------------------------------------------------------------------------
__global__ __launch_bounds__(512) void gemm8(
    const bf16_t* __restrict__ X,
    const bf16_t* __restrict__ W0, const bf16_t* __restrict__ W1,
    const float* __restrict__ bias0, const float* __restrict__ bias1,
    bf16_t* __restrict__ outK, bf16_t* __restrict__ outV,
    const bf16_t* __restrict__ X2, const bf16_t* __restrict__ W2,
    const float* __restrict__ bias2, bf16_t* __restrict__ outQ)
{
    constexpr int BUFSZ = 49152;                  // A 32K + B 16K
    __shared__ __align__(16) char smem[3 * BUFSZ];

    const int t = threadIdx.x;
    const int lane = t & 63, w = t >> 6;          // w in [0,8)
    const int quad = lane >> 4, l15 = lane & 15;
    const int wm = w >> 1, wn = w & 1;            // 4M x 2N wave grid

    int emode = 1, nt = 12, bid = blockIdx.x;
    const bf16_t* Xp = X;
    const bf16_t* Wp = W0;
    const float*  b0 = bias0;
    if (bid >= 576) {                             // Q region
        emode = 0; nt = 6; bid -= 576;
        Xp = X2; Wp = W2; b0 = bias2;
    }

    // XCD-aware swizzle
    const int xcd = bid & 7, jj = bid >> 3;
    const int n_t = jj % nt, slab = jj / nt;
    const int m0 = (slab * 8 + xcd) * 256;
    const int n0 = n_t * 128;

    const bf16_t* Wsel = (emode == 1 && n0 >= 768) ? W1 : Wp;
    const int n0b = (emode == 1 && n0 >= 768) ? n0 - 768 : n0;

    const bf16_t* sp[6];
    int loff[6];
#pragma unroll
    for (int i = 0; i < 6; i++) {
        int g = w * 6 + i;
        loff[i] = g * 1024;
        if (g < 32) {
            int ks = g >> 4, mt = g & 15;
            sp[i] = Xp + (size_t)(m0 + mt * 16 + l15) * NHID + ks * 32 + quad * 8;
        } else {
            int gb = g - 32;
            int ks = gb >> 3, ntile = gb & 7;
            sp[i] = Wsel + (size_t)(n0b + ntile * 16 + l15) * NHID + ks * 32 + quad * 8;
        }
    }

    auto stage_half = [&](char* base, int h) {     // 3 instrs per half
#pragma unroll
        for (int i = 0; i < 3; i++) {
            int idx = h * 3 + i;
            gl_lds16(sp[idx], base + loff[idx]);
            sp[idx] += 64;                         // BK=64 elements
        }
    };

    f32x4 acc[4][4];
#pragma unroll
    for (int i = 0; i < 4; i++)
#pragma unroll
        for (int j = 0; j < 4; j++) acc[i][j] = 0.0f;

    constexpr int KITER = NHID / 64;               // 12
    stage_half(smem, 0);          stage_half(smem, 1);           // stage(0)
    stage_half(smem + BUFSZ, 0);  stage_half(smem + BUFSZ, 1);   // stage(1)

    for (int it = 0; it < KITER; ++it) {
        if (it == KITER - 1) asm volatile("s_waitcnt vmcnt(0)" ::: "memory");
        else                 asm volatile("s_waitcnt vmcnt(6)" ::: "memory");
        __builtin_amdgcn_s_barrier();              // all waves' stage(it) done

        const char* rb = smem + (it % 3) * BUFSZ;
        char* pb = smem + ((it + 2) % 3) * BUFSZ;
        const bool dostage = (it + 2 < KITER);

#pragma unroll
        for (int ks = 0; ks < 2; ++ks) {           // 2 phases per iteration
            bf16x8 af[4], bfr[4];
#pragma unroll
            for (int i = 0; i < 4; i++)
                af[i] = *(const bf16x8*)(rb + (ks * 16 + wm * 4 + i) * 1024 + lane * 16);
#pragma unroll
            for (int j = 0; j < 4; j++)
                bfr[j] = *(const bf16x8*)(rb + 32768 + (ks * 8 + wn * 4 + j) * 1024 + lane * 16);
            if (dostage) stage_half(pb, ks);
            __builtin_amdgcn_s_setprio(1);
#pragma unroll
            for (int i = 0; i < 4; i++)
#pragma unroll
                for (int j = 0; j < 4; j++)
                    acc[i][j] = MFMA(af[i], bfr[j], acc[i][j]);
            __builtin_amdgcn_s_setprio(0);
            if (ks == 0) __builtin_amdgcn_s_barrier();   // phase boundary
        }
    }

    // ---- epilogue: per-wave 64x64 at (m0 + wm*64, n0 + wn*64) ----
#pragma unroll
    for (int i = 0; i < 4; i++) {
#pragma unroll
        for (int j = 0; j < 4; j++) {
            const int n = n0 + wn * 64 + j * 16 + l15;
            float bn;
            if (emode == 1) bn = (n < 768) ? b0[n] : bias1[n - 768];
            else            bn = b0[n];
            if (emode == 1 && n >= 768) {
                // Vp layout, bf16x4-packed (rg -> consecutive e-slots)
                const int m = m0 + wm * 64 + i * 16 + quad * 4;
                int b = m / (NA * NS);
                int rem = m - b * (NA * NS);
                int a = rem >> 10, s = rem & 1023;
                int hh = (n - 768) >> 6;
                bf16x4 pk;
#pragma unroll
                for (int rg = 0; rg < 4; rg++) pk[rg] = (bf16_t)(acc[i][j][rg] + bn);
                char* dst = (char*)outV + (size_t)((b * NHEADS + hh) * NA + a) * 131072
                            + (size_t)(s >> 5) * 4096 + j * 1024
                            + (quad * 16 + l15) * 16 + (i & 1) * 8;
                *reinterpret_cast<bf16x4*>(dst) = pk;
            } else {
#pragma unroll
                for (int rg = 0; rg < 4; rg++) {
                    const int m = m0 + wm * 64 + i * 16 + quad * 4 + rg;
                    float v = acc[i][j][rg] + bn;
                    if (emode == 0) {
                        v *= QSCALE;   // fold softmax scale into Q
                        int b = m >> 10, s = m & 1023, hh = n >> 6, d = n & 63;
                        outQ[(((size_t)(b * NHEADS + hh) * NS) + s) * HD + d] = (bf16_t)v;
                    } else {
                        int b = m / (NA * NS);
                        int rem = m - b * (NA * NS);
                        int a = rem >> 10, s = rem & 1023;
                        int hh = n >> 6, d = n & 63;
                        outK[((((size_t)(b * NHEADS + hh) * NA + a) * NS) + s) * HD + d] = (bf16_t)v;
                    }
                }
            }
        }
    }
}

// ---------------------------------------------------------------------------
// R19 oproj4: O-projection fused with residual. Tile 128x96, BK=64 ->
// 12 iterations (half of proj_gemm's 24 serial phases); grid 32m x 8n =
// 256 blocks -> EVERY CU gets a block (proj_gemm<3>'s 192 left 64 CUs
// idle and its 24-iter per-block latency chain dominated). 4 waves (2x2),
// per-wave 64x48 (4x3 frags). LDS 2 x (A 16K + B 12K) = 56KB -> 2
// blocks/CU. R15 discipline: stage(it+1) -> vmcnt(7) -> barrier ->
// ds_read + 24 MFMA -> raw barrier.
// ---------------------------------------------------------------------------
__global__ __launch_bounds__(256) void oproj4(
    const bf16_t* __restrict__ X, const bf16_t* __restrict__ W,
    const float* __restrict__ bias, const float* __restrict__ resid,
    float* __restrict__ outf)
{
    constexpr int BUFSZ = 28672;                 // A 16K + B 12K
    __shared__ __align__(16) char smem[2 * BUFSZ];

    const int t = threadIdx.x;
    const int lane = t & 63, w = t >> 6;
    const int quad = lane >> 4, l15 = lane & 15;
    const int wm = w >> 1, wn = w & 1;

    const int bid = blockIdx.x;                  // [0,256)
    const int xcd = bid & 7, jj = bid >> 3;      // jj in [0,32)
    const int n_t = jj % 8, slab = jj / 8;       // slab in [0,4)
    const int m0 = (slab * 8 + xcd) * 128;
    const int n0 = n_t * 96;

    // 28 staging instrs (A 16 + B 12), 7 per wave.
    const bf16_t* sp[7];
    int loff[7];
#pragma unroll
    for (int i = 0; i < 7; i++) {
        int g = w * 7 + i;
        if (g < 16) {            // A: ks = g>>3, mt = g&7
            int ks = g >> 3, mt = g & 7;
            sp[i] = X + (size_t)(m0 + mt * 16 + l15) * NHID + ks * 32 + quad * 8;
            loff[i] = g * 1024;
        } else {                 // B: gb = g-16: ks = gb/6, ntile = gb%6
            int gb = g - 16;
            int ks = gb / 6, ntile = gb - ks * 6;
            sp[i] = W + (size_t)(n0 + ntile * 16 + l15) * NHID + ks * 32 + quad * 8;
            loff[i] = 16384 + gb * 1024;
        }
    }

    auto stage = [&](char* base) {
#pragma unroll
        for (int i = 0; i < 7; i++) {
            gl_lds16(sp[i], base + loff[i]);
            sp[i] += 64;                         // BK=64
        }
    };

    f32x4 acc[4][3];
#pragma unroll
    for (int i = 0; i < 4; i++)
#pragma unroll
        for (int j = 0; j < 3; j++) acc[i][j] = 0.0f;

    constexpr int KITER = NHID / 64;             // 12
    stage(smem);

    for (int it = 0; it < KITER; ++it) {
        if (it + 1 < KITER) {
            stage(smem + ((it + 1) & 1) * BUFSZ);
            asm volatile("s_waitcnt vmcnt(7)" ::: "memory");   // stage(it) done
        } else {
            asm volatile("s_waitcnt vmcnt(0)" ::: "memory");
        }
        __builtin_amdgcn_s_barrier();

        const char* rb = smem + (it & 1) * BUFSZ;
#pragma unroll
        for (int ks = 0; ks < 2; ++ks) {
            bf16x8 af[4], bfr[3];
#pragma unroll
            for (int i = 0; i < 4; i++)
                af[i] = *(const bf16x8*)(rb + (ks * 8 + wm * 4 + i) * 1024 + lane * 16);
#pragma unroll
            for (int j = 0; j < 3; j++)
                bfr[j] = *(const bf16x8*)(rb + 16384 + (ks * 6 + wn * 3 + j) * 1024 + lane * 16);
#pragma unroll
            for (int i = 0; i < 4; i++)
#pragma unroll
                for (int j = 0; j < 3; j++)
                    acc[i][j] = MFMA(af[i], bfr[j], acc[i][j]);
        }
        __builtin_amdgcn_s_barrier();            // raw: guards buffer reuse
    }

    // epilogue: per-wave 64x48 at (m0 + wm*64, n0 + wn*48); fp32 + resid
#pragma unroll
    for (int i = 0; i < 4; i++) {
#pragma unroll
        for (int j = 0; j < 3; j++) {
            const int n = n0 + wn * 48 + j * 16 + l15;
            const float bn = bias[n];
#pragma unroll
            for (int rg = 0; rg < 4; rg++) {
                const int m = m0 + wm * 64 + i * 16 + quad * 4 + rg;
                float v = acc[i][j][rg] + bn + resid[(size_t)m * NHID + n];
                outf[(size_t)m * NHID + n] = v;
            }
        }
    }
}

// ---------------------------------------------------------------------------
// Projection GEMM (R15 structure) -- fallback tiers 2/3 only.
// 128x128 tile, BK=32, 4 waves, 2 buffers + 2 raw barriers + counted vmcnt.
// MODE 0 epilogue pre-scales by QSCALE.
// ---------------------------------------------------------------------------
template <int MODE, int NT, bool ABF, bool BBF>
__global__ __launch_bounds__(256) void proj_gemm(
    const void* __restrict__ Xv,
    const void* __restrict__ W0v, const void* __restrict__ W1v,
    const float* __restrict__ bias0, const float* __restrict__ bias1,
    const float* __restrict__ resid,
    bf16_t* __restrict__ out0, bf16_t* __restrict__ out1,
    float* __restrict__ outf)
{
    constexpr int ASZ   = ABF ? 8192 : 16384;
    constexpr int BSZ   = BBF ? 8192 : 16384;
    constexpr int BUFSZ = ASZ + BSZ;
    constexpr int LPS   = (ABF ? 2 : 4) + (BBF ? 2 : 4);
    __shared__ __align__(16) char smem[2 * BUFSZ];

    const int t = threadIdx.x;
    const int lane = t & 63, w = t >> 6;
    const int quad = lane >> 4, l15 = lane & 15;
    const int wm = w >> 1, wn = w & 1;

    const int bid = blockIdx.x;
    const int xcd = bid & 7, jj = bid >> 3;
    const int n_t = jj % NT, slab = jj / NT;
    const int m0 = (slab * 8 + xcd) * 128;
    const int n0 = n_t * 128;

    const void* Wselv = (MODE == 1 && n0 >= 768) ? W1v : W0v;
    const int n0b = (MODE == 1 && n0 >= 768) ? n0 - 768 : n0;

    const int srow  = lane >> 3;
    const int schnk = (lane & 7) ^ srow;
    const float*  Apf[4];
    const bf16_t* Apb[2];
    const float*  Bpf[4];
    const bf16_t* Bpb[2];
    if constexpr (ABF) {
        const bf16_t* X = (const bf16_t*)Xv;
#pragma unroll
        for (int i = 0; i < 2; i++) {
            int g = w * 2 + i;
            Apb[i] = X + (size_t)(m0 + g * 16 + l15) * NHID + quad * 8;
        }
    } else {
        const float* X = (const float*)Xv;
#pragma unroll
        for (int i = 0; i < 4; i++) {
            int g = w * 4 + i;
            Apf[i] = X + (size_t)(m0 + g * 8 + srow) * NHID + schnk * 4;
        }
    }
    if constexpr (BBF) {
        const bf16_t* Wb = (const bf16_t*)Wselv;
#pragma unroll
        for (int i = 0; i < 2; i++) {
            int g = w * 2 + i;
            Bpb[i] = Wb + (size_t)(n0b + g * 16 + l15) * NHID + quad * 8;
        }
    } else {
        const float* Wf = (const float*)Wselv;
#pragma unroll
        for (int i = 0; i < 4; i++) {
            int g = w * 4 + i;
            Bpf[i] = Wf + (size_t)(n0b + g * 8 + srow) * NHID + schnk * 4;
        }
    }

    auto stage = [&](char* base) {
        char* Ab = base;
        char* Bb = base + ASZ;
        if constexpr (ABF) {
#pragma unroll
            for (int i = 0; i < 2; i++) { gl_lds16(Apb[i], Ab + (w * 2 + i) * 1024); Apb[i] += 32; }
        } else {
#pragma unroll
            for (int i = 0; i < 4; i++) { gl_lds16(Apf[i], Ab + (w * 4 + i) * 1024); Apf[i] += 32; }
        }
        if constexpr (BBF) {
#pragma unroll
            for (int i = 0; i < 2; i++) { gl_lds16(Bpb[i], Bb + (w * 2 + i) * 1024); Bpb[i] += 32; }
        } else {
#pragma unroll
            for (int i = 0; i < 4; i++) { gl_lds16(Bpf[i], Bb + (w * 4 + i) * 1024); Bpf[i] += 32; }
        }
    };

    auto wait_one = [&]() {
        if constexpr (LPS == 4)      asm volatile("s_waitcnt vmcnt(4)" ::: "memory");
        else if constexpr (LPS == 6) asm volatile("s_waitcnt vmcnt(6)" ::: "memory");
        else                         asm volatile("s_waitcnt vmcnt(8)" ::: "memory");
    };

    f32x4 acc[4][4];
#pragma unroll
    for (int i = 0; i < 4; i++)
#pragma unroll
        for (int j = 0; j < 4; j++) acc[i][j] = 0.0f;

    constexpr int KITER = NHID / 32;   // 24
    stage(smem);

    for (int it = 0; it < KITER; ++it) {
        if (it + 1 < KITER) {
            stage(smem + ((it + 1) & 1) * BUFSZ);
            wait_one();
        } else {
            asm volatile("s_waitcnt vmcnt(0)" ::: "memory");
        }
        __builtin_amdgcn_s_barrier();

        char* Ab = smem + (it & 1) * BUFSZ;
        char* Bb = Ab + ASZ;

        bf16x8 af[4], bfr[4];
        const int pl = (2 * quad) ^ (l15 & 7);
#pragma unroll
        for (int i = 0; i < 4; i++) {
            if constexpr (ABF) {
                int mt = wm * 4 + i;
                af[i] = *(const bf16x8*)(Ab + (mt * 64 + lane) * 16);
            } else {
                int R = (wm * 4 + i) * 16 + l15;
                f32x4 lo = *(const f32x4*)(Ab + R * 128 + pl * 16);
                f32x4 hi = *(const f32x4*)(Ab + R * 128 + (pl ^ 1) * 16);
                af[i] = cvt8(lo, hi);
            }
        }
#pragma unroll
        for (int j = 0; j < 4; j++) {
            if constexpr (BBF) {
                int ntj = wn * 4 + j;
                bfr[j] = *(const bf16x8*)(Bb + (ntj * 64 + lane) * 16);
            } else {
                int R = (wn * 4 + j) * 16 + l15;
                f32x4 lo = *(const f32x4*)(Bb + R * 128 + pl * 16);
                f32x4 hi = *(const f32x4*)(Bb + R * 128 + (pl ^ 1) * 16);
                bfr[j] = cvt8(lo, hi);
            }
        }
#pragma unroll
        for (int i = 0; i < 4; i++)
#pragma unroll
            for (int j = 0; j < 4; j++)
                acc[i][j] = MFMA(af[i], bfr[j], acc[i][j]);
        __builtin_amdgcn_s_barrier();
    }

#pragma unroll
    for (int i = 0; i < 4; i++) {
#pragma unroll
        for (int j = 0; j < 4; j++) {
            const int n = n0 + wn * 64 + j * 16 + l15;
            float bn;
            if (MODE == 1) bn = (n < 768) ? bias0[n] : bias1[n - 768];
            else           bn = bias0[n];
            if (MODE == 1 && n >= 768) {
                const int m = m0 + wm * 64 + i * 16 + quad * 4;
                int b = m / (NA * NS);
                int rem = m - b * (NA * NS);
                int a = rem >> 10, s = rem & 1023;
                int hh = (n - 768) >> 6;
                bf16x4 pk;
#pragma unroll
                for (int rg = 0; rg < 4; rg++) pk[rg] = (bf16_t)(acc[i][j][rg] + bn);
                char* dst = (char*)out1 + (size_t)((b * NHEADS + hh) * NA + a) * 131072
                            + (size_t)(s >> 5) * 4096 + j * 1024
                            + (quad * 16 + l15) * 16 + (i & 1) * 8;
                *reinterpret_cast<bf16x4*>(dst) = pk;
            } else {
#pragma unroll
                for (int rg = 0; rg < 4; rg++) {
                    const int m = m0 + wm * 64 + i * 16 + quad * 4 + rg;
                    float v = acc[i][j][rg] + bn;
                    if (MODE == 0) {
                        v *= QSCALE;   // fold softmax scale into Q
                        int b = m >> 10, s = m & 1023, hh = n >> 6, d = n & 63;
                        out0[(((size_t)(b * NHEADS + hh) * NS) + s) * HD + d] = (bf16_t)v;
                    } else if (MODE == 1) {
                        int b = m / (NA * NS);
                        int rem = m - b * (NA * NS);
                        int a = rem >> 10, s = rem & 1023;
                        int hh = n >> 6, d = n & 63;
                        out0[((((size_t)(b * NHEADS + hh) * NA + a) * NS) + s) * HD + d] = (bf16_t)v;
                    } else {
                        v += resid[(size_t)m * NHID + n];
                        outf[(size_t)m * NHID + n] = v;
                    }
                }
            }
        }
    }
}

// ---------------------------------------------------------------------------
// Attention R19 = R16 structure (proven best total) + QSCALE'd Q:
// block = 4 waves x 16 q-rows (qt = (qblk<<2)|w), 768 blocks, 3 blocks/CU
// = 12 waves/CU (R17/R18's 2-tile amortization halved wave count to 6/CU
// and lost more to the VALU-latency-bound softmax than it saved in LDS
// reads). Swapped QK^T, in-register softmax (exp2 direct -- Q pre-scaled),
// Vp-matched PV, counted-vmcnt(6) + 2 raw barriers.
// ---------------------------------------------------------------------------
__global__ __launch_bounds__(256, 3) void attn_kernel(
    const bf16_t* __restrict__ Q, const bf16_t* __restrict__ K,
    const bf16_t* __restrict__ VT, bf16_t* __restrict__ AT)
{
    __shared__ __align__(16) char kv[2 * 24576];        // 2 x (K 12K + V 12K)

    const int t    = threadIdx.x;
    const int w    = t >> 6, lane = t & 63;
    const int quad = lane >> 4, l15 = lane & 15;

    int bh, qt;
    if (gridDim.x == 768) {           // full launch: XCD-local bh
        int xcd = blockIdx.x & 7, j = blockIdx.x >> 3;
        bh = (j >> 4) * 8 + xcd;      // 6 slabs x 8 xcd = 48
        qt = ((j & 15) << 2) | w;     // wave-level q-tiling: 0..63
    } else {                          // per-batch fallback
        bh = blockIdx.x >> 4;
        qt = ((blockIdx.x & 15) << 2) | w;
    }
    const int b  = bh / NHEADS, h = bh - b * NHEADS;
    const int q0 = qt * 16;

    const bf16_t* Qb = Q + ((size_t)bh * NS + q0) * HD;
    bf16x8 qf0 = load8(Qb + l15 * HD + quad * 8);
    bf16x8 qf1 = load8(Qb + l15 * HD + quad * 8 + 32);

    // staging: 6 groups per wave (24 total: 12 K + 12 V); all strides 4096B
    const char* gp[6];
    int loff[6];
#pragma unroll
    for (int i = 0; i < 6; i++) {
        int g = w * 6 + i;
        loff[i] = g >= 12 ? 12288 + (g - 12) * 1024 : g * 1024;
        if (g < 12) {   // K: a|j|dh
            int a = g >> 2, j = (g >> 1) & 1, dh = g & 1;
            gp[i] = (const char*)(K + ((size_t)(bh * NA + a) * NS + j * 16 + l15) * HD
                                  + dh * 32 + quad * 8);
        } else {        // Vp: a|dt -- contiguous 1KB per instr
            int gi = g - 12;
            int a = gi >> 2, dt = gi & 3;
            gp[i] = (const char*)VT + (size_t)(bh * NA + a) * 131072
                    + dt * 1024 + (size_t)lane * 16;
        }
    }

    auto stage = [&](int buf) {
#pragma unroll
        for (int i = 0; i < 6; i++) {
            gl_lds16(gp[i], kv + buf * 24576 + loff[i]);
            gp[i] += 4096;
        }
    };

    f32x4 acc[4];
#pragma unroll
    for (int dt = 0; dt < 4; dt++) acc[dt] = 0.0f;

    stage(0);

    for (int it = 0; it < 32; ++it) {
        if (it + 1 < 32) {
            stage((it + 1) & 1);
            asm volatile("s_waitcnt vmcnt(6)" ::: "memory");  // stage(it) done
        } else {
            asm volatile("s_waitcnt vmcnt(0)" ::: "memory");
        }
        __builtin_amdgcn_s_barrier();

        const char* base = kv + (it & 1) * 24576;
        // swapped QK^T: D[row=s][col=q]; lane: q = l15, s = j*16 + quad*4+rg
        f32x4 sc[3][2];
#pragma unroll
        for (int a = 0; a < 3; a++) {
#pragma unroll
            for (int j = 0; j < 2; j++) {
                bf16x8 klo = *(const bf16x8*)(base + ((a * 4 + j * 2 + 0) * 64 + lane) * 16);
                bf16x8 khi = *(const bf16x8*)(base + ((a * 4 + j * 2 + 1) * 64 + lane) * 16);
                f32x4 z = 0.0f;
                f32x4 c0 = MFMA(klo, qf0, z);
                sc[a][j] = MFMA(khi, qf1, c0);
            }
        }
        // 3-exp softmax over adapters (Q pre-scaled: exp2(x-mx) direct)
        f32x4 plo[3], phi[3];
#pragma unroll
        for (int j = 0; j < 2; j++) {
#pragma unroll
            for (int rg = 0; rg < 4; rg++) {
                float x0 = sc[0][j][rg], x1 = sc[1][j][rg], x2 = sc[2][j][rg];
                float mx = fmaxf(x0, fmaxf(x1, x2));
                float e0 = __builtin_amdgcn_exp2f(x0 - mx);
                float e1 = __builtin_amdgcn_exp2f(x1 - mx);
                float e2 = __builtin_amdgcn_exp2f(x2 - mx);
                float inv = __builtin_amdgcn_rcpf(e0 + e1 + e2);
                if (j == 0) {
                    plo[0][rg] = e0 * inv; plo[1][rg] = e1 * inv; plo[2][rg] = e2 * inv;
                } else {
                    phi[0][rg] = e0 * inv; phi[1][rg] = e1 * inv; phi[2][rg] = e2 * inv;
                }
            }
        }
        // PV: P packed in-register; k-order matches Vp fragments.
#pragma unroll
        for (int a = 0; a < 3; a++) {
            bf16x8 pf = cvt8(plo[a], phi[a]);
#pragma unroll
            for (int dt = 0; dt < 4; dt++) {
                bf16x8 vf = *(const bf16x8*)(base + 12288 + ((a * 4 + dt) * 64 + lane) * 16);
                acc[dt] = MFMA(pf, vf, acc[dt]);
            }
        }
        __builtin_amdgcn_s_barrier();  // raw: guards buffer reuse
    }

    bf16_t* Ob = AT + (size_t)b * NS * NHID;
#pragma unroll
    for (int dt = 0; dt < 4; dt++) {
#pragma unroll
        for (int rg = 0; rg < 4; rg++) {
            int qq = q0 + quad * 4 + rg;
            Ob[(size_t)qq * NHID + h * HD + dt * 16 + l15] = (bf16_t)acc[dt][rg];
        }
    }
}

// ---------------------------------------------------------------------------
// LayerNorm over rows of X (fp32, [4096,768]), IN PLACE. Also fills its
// 1024-float slice of avg_weights (=1/3).
// ---------------------------------------------------------------------------
__global__ __launch_bounds__(256) void ln_kernel(
    float* __restrict__ X, const float* __restrict__ gamma,
    const float* __restrict__ beta, float* __restrict__ avgw)
{
    const int row = blockIdx.x;
    const int t = threadIdx.x;
    float* x = X + (size_t)row * NHID;
    float v0 = x[t], v1 = x[t + 256], v2 = x[t + 512];
    float s  = v0 + v1 + v2;
    float s2 = v0 * v0 + v1 * v1 + v2 * v2;
#pragma unroll
    for (int off = 32; off > 0; off >>= 1) {
        s  += __shfl_down(s, off);
        s2 += __shfl_down(s2, off);
    }
    __shared__ float red[8];
    const int w = t >> 6, lane = t & 63;
    if (lane == 0) { red[w] = s; red[4 + w] = s2; }
    __syncthreads();
    s  = red[0] + red[1] + red[2] + red[3];
    s2 = red[4] + red[5] + red[6] + red[7];
    float mu  = s * (1.0f / NHID);
    float var = s2 * (1.0f / NHID) - mu * mu;
    float rs  = rsqrtf(fmaxf(var, 0.0f) + 1e-5f);
    x[t]       = (v0 - mu) * rs * gamma[t]       + beta[t];
    x[t + 256] = (v1 - mu) * rs * gamma[t + 256] + beta[t + 256];
    x[t + 512] = (v2 - mu) * rs * gamma[t + 512] + beta[t + 512];
    // avg_weights: 1/3 identically; each block owns 1024 floats
    f32x4 v3 = { 1.0f / 3.0f, 1.0f / 3.0f, 1.0f / 3.0f, 1.0f / 3.0f };
    reinterpret_cast<f32x4*>(avgw)[(size_t)row * 256 + t] = v3;
}

// ---------------------------------------------------------------------------
// out0 [0,12.58MB) fp32: O-proj X -> LN in place. out1: bf16 scratch.
// ws tier 1 (>=67,633,152 B): K 18.87 | Vp 18.87 | adaptb 18.87 | Wqb/Wkb/
// Wvb/Wob 1.18 ea | queryb 6.29 MB. tier 2 (>=37,748,736): K | Vp only.
// ---------------------------------------------------------------------------
extern "C" void kernel_launch(void* const* d_in, const int* in_sizes, int n_in,
                              void* d_out, int out_size, void* d_ws, size_t ws_size,
                              hipStream_t stream)
{
    (void)in_sizes; (void)n_in; (void)out_size;
    const float* query = (const float*)d_in[0];
    const float* adapt = (const float*)d_in[1];
    const float* Wq    = (const float*)d_in[2];
    const float* bq    = (const float*)d_in[3];
    const float* Wk    = (const float*)d_in[4];
    const float* bk    = (const float*)d_in[5];
    const float* Wv    = (const float*)d_in[6];
    const float* bv    = (const float*)d_in[7];
    const float* Wo    = (const float*)d_in[8];
    const float* bo    = (const float*)d_in[9];
    const float* gamma = (const float*)d_in[10];
    const float* beta  = (const float*)d_in[11];

    float*  out0  = (float*)d_out;            // 3,145,728 fp32
    float*  out1f = out0 + 3145728;           // 4,194,304 fp32
    bf16_t* out1b = (bf16_t*)out1f;

    dim3 blk(256);

    if (ws_size >= (size_t)67633152) {
        // ---- tier 1: cvt -> gemm8 QKV -> attn -> oproj4 -> ln ----
        bf16_t* Kw  = (bf16_t*)d_ws;
        bf16_t* VTw = (bf16_t*)((char*)d_ws + 18874368);
        bf16_t* Adb = (bf16_t*)((char*)d_ws + 37748736);   // adapt bf16
        bf16_t* Wqb = (bf16_t*)((char*)d_ws + 56623104);
        bf16_t* Wkb = (bf16_t*)((char*)d_ws + 57802752);
        bf16_t* Wvb = (bf16_t*)((char*)d_ws + 58982400);
        bf16_t* Wob = (bf16_t*)((char*)d_ws + 60162048);
        bf16_t* Qcb = (bf16_t*)((char*)d_ws + 61341696);   // query bf16
        bf16_t* Qw  = out1b;
        bf16_t* ATw = out1b + 3145728;
        // bulk fp32->bf16: adapt 2304 | query 768 | Wq/Wk/Wv/Wo 144 each
        cvt6<<<dim3(3648), blk, 0, stream>>>(
            adapt, Adb, 2304, query, Qcb, 3072,
            Wq, Wqb, 3216, Wk, Wkb, 3360, Wv, Wvb, 3504, Wo, Wob, 3648);
        // merged QKV: 576 KV blocks (256x128) + 96 Q blocks
        gemm8<<<dim3(672), dim3(512), 0, stream>>>(
            Adb, Wkb, Wvb, bk, bv, Kw, VTw, Qcb, Wqb, bq, Qw);
        attn_kernel<<<dim3(768), blk, 0, stream>>>(Qw, Kw, VTw, ATw);
        oproj4<<<dim3(256), blk, 0, stream>>>(ATw, Wob, bo, query, out0);
    } else if (ws_size >= (size_t)37748736) {
        // ---- tier 2: bf16 B only (W's in out1 spare), fp32 A ----
        bf16_t* Kw  = (bf16_t*)d_ws;
        bf16_t* VTw = (bf16_t*)((char*)d_ws + 18874368);
        bf16_t* Qw  = out1b;
        bf16_t* ATw = out1b + 3145728;
        bf16_t* Wqb = out1b + 6291456;         // 4.19MB spare in out1
        bf16_t* Wkb = Wqb + 589824;
        bf16_t* Wvb = Wkb + 589824;
        cvt6<<<dim3(432), blk, 0, stream>>>(
            Wq, Wqb, 144, Wk, Wkb, 288, Wv, Wvb, 432,
            Wv, Wvb, 432, Wv, Wvb, 432, Wv, Wvb, 432);
        proj_gemm<0, 6, false, true><<<dim3(192), blk, 0, stream>>>(
            query, Wqb, nullptr, bq, nullptr, nullptr, Qw, nullptr, nullptr);
        proj_gemm<1, 12, false, true><<<dim3(1152), blk, 0, stream>>>(
            adapt, Wkb, Wvb, bk, bv, nullptr, Kw, VTw, nullptr);
        attn_kernel<<<dim3(768), blk, 0, stream>>>(Qw, Kw, VTw, ATw);
        proj_gemm<3, 6, true, false><<<dim3(192), blk, 0, stream>>>(
            ATw, Wo, nullptr, bo, nullptr, query, nullptr, nullptr, out0);
    } else {
        // per-batch, zero-workspace fallback (scratch inside out1)
        bf16_t* Qc  = out1b;                  //   786,432 bf16
        bf16_t* ATc = out1b + 786432;         //   786,432 bf16
        bf16_t* Kc  = out1b + 1572864;        // 2,359,296 bf16
        bf16_t* VTc = out1b + 3932160;        // 2,359,296 bf16
        for (int b = 0; b < NB; b++) {
            const float* qb = query + (size_t)b * NS * NHID;
            const float* ab = adapt + (size_t)b * NA * NS * NHID;
            proj_gemm<0, 6, false, false><<<dim3(48), blk, 0, stream>>>(
                qb, Wq, nullptr, bq, nullptr, nullptr, Qc, nullptr, nullptr);
            proj_gemm<1, 12, false, false><<<dim3(288), blk, 0, stream>>>(
                ab, Wk, Wv, bk, bv, nullptr, Kc, VTc, nullptr);
            attn_kernel<<<dim3(192), blk, 0, stream>>>(Qc, Kc, VTc, ATc);
            proj_gemm<3, 6, true, false><<<dim3(48), blk, 0, stream>>>(
                ATc, Wo, nullptr, bo, nullptr, qb, nullptr, nullptr,
                out0 + (size_t)b * NS * NHID);
        }
    }

    ln_kernel<<<dim3(4096), blk, 0, stream>>>(out0, gamma, beta, out1f);
}